// Round 1
// baseline (1139.956 us; speedup 1.0000x reference)
//
#include <hip/hip_runtime.h>
#include <hip/hip_bf16.h>

#define NTOK 8192
#define DDIM 512
#define FDIM 2048
#define ENUM 8

typedef __bf16 bf16x8 __attribute__((ext_vector_type(8)));
typedef short short8 __attribute__((ext_vector_type(8)));
typedef float f32x4 __attribute__((ext_vector_type(4)));

// ---- workspace byte offsets ----
#define WS_COUNTS   0ULL        // int[8]   (zeroed)
#define WS_PSUM     32ULL       // float[8] (zeroed)
#define WS_ZSUM     64ULL       // float    (zeroed)
#define WS_OFFSETS  128ULL      // int[8]
#define WS_TKEPOS   256ULL      // int[2N]
#define WS_TKWT     65792ULL    // float[2N]
#define WS_IDXLIST  131328ULL   // int[E*N]
#define WS_TOKBF    393472ULL   // bf16[N*D]
#define WS_W1T      8782080ULL  // bf16[E*F*D]  (transposed: [e][f][d])
#define WS_W2T      25559296ULL // bf16[E*D*F]  (transposed: [e][d][f])
#define WS_H        42336512ULL // bf16[2N * F]
#define WS_O        109445376ULL// float[2N * D]

__device__ __forceinline__ unsigned short f2bf_bits(float f) {
    unsigned int u = __builtin_bit_cast(unsigned int, f);
    unsigned int r = (u + 0x7FFFu + ((u >> 16) & 1u)) >> 16;
    return (unsigned short)r;
}

__device__ __forceinline__ float gelu_tanh(float x) {
    float u = 0.7978845608028654f * (x + 0.044715f * x * x * x);
    return 0.5f * x * (1.0f + tanhf(u));
}

// ---- tokens f32 -> bf16 ----
__global__ __launch_bounds__(256) void k_convert_tok(const float* __restrict__ in,
                                                     unsigned short* __restrict__ out) {
    int i = blockIdx.x * 256 + threadIdx.x;      // 524288 chunks of 8 floats
    const float4* in4 = (const float4*)in;
    float4 a = in4[2 * (size_t)i];
    float4 b = in4[2 * (size_t)i + 1];
    short8 r;
    r[0] = (short)f2bf_bits(a.x); r[1] = (short)f2bf_bits(a.y);
    r[2] = (short)f2bf_bits(a.z); r[3] = (short)f2bf_bits(a.w);
    r[4] = (short)f2bf_bits(b.x); r[5] = (short)f2bf_bits(b.y);
    r[6] = (short)f2bf_bits(b.z); r[7] = (short)f2bf_bits(b.w);
    *(short8*)(out + 8 * (size_t)i) = r;
}

// ---- transpose [E][R][C] f32 -> [E][C][R] bf16 ----
__global__ __launch_bounds__(256) void k_transpose_bf16(const float* __restrict__ in,
                                                        unsigned short* __restrict__ out,
                                                        int R, int C) {
    __shared__ float tile[32][33];
    int e = blockIdx.z;
    int c0 = blockIdx.x << 5, r0 = blockIdx.y << 5;
    const float* ip = in + (size_t)e * R * C;
    unsigned short* op = out + (size_t)e * R * C;
    int tx = threadIdx.x, ty = threadIdx.y;
#pragma unroll
    for (int i = 0; i < 4; i++)
        tile[ty + i * 8][tx] = ip[(size_t)(r0 + ty + i * 8) * C + c0 + tx];
    __syncthreads();
#pragma unroll
    for (int i = 0; i < 4; i++)
        op[(size_t)(c0 + ty + i * 8) * R + r0 + tx] = f2bf_bits(tile[tx][ty + i * 8]);
}

// ---- gating: wave per token, 8 tokens per wave (grid-stride) ----
__global__ __launch_bounds__(256) void k_gate(const float* __restrict__ tok,
                                              const float* __restrict__ gw,
                                              float* __restrict__ out_logits,
                                              float* __restrict__ out_probs,
                                              int* __restrict__ counts,
                                              float* __restrict__ psum,
                                              float* __restrict__ zsum,
                                              int* __restrict__ idx_list,
                                              int* __restrict__ tk_epos,
                                              float* __restrict__ tk_wt) {
    int lane = threadIdx.x & 63;
    int wid = blockIdx.x * (blockDim.x >> 6) + (threadIdx.x >> 6);  // 0..1023
    float accP[8] = {0, 0, 0, 0, 0, 0, 0, 0};
    float accZ = 0.f;
    for (int t = 0; t < 8; ++t) {
        int n = wid * 8 + t;
        const float* tp = tok + (size_t)n * DDIM + lane * 8;
        float4 x0 = *(const float4*)tp;
        float4 x1 = *(const float4*)(tp + 4);
        float lg[8] = {0, 0, 0, 0, 0, 0, 0, 0};
#pragma unroll
        for (int j = 0; j < 8; j++) {
            float xv = (j < 4) ? ((const float*)&x0)[j] : ((const float*)&x1)[j - 4];
            const float4 g0 = *(const float4*)&gw[(lane * 8 + j) * 8];
            const float4 g1 = *(const float4*)&gw[(lane * 8 + j) * 8 + 4];
            lg[0] += xv * g0.x; lg[1] += xv * g0.y; lg[2] += xv * g0.z; lg[3] += xv * g0.w;
            lg[4] += xv * g1.x; lg[5] += xv * g1.y; lg[6] += xv * g1.z; lg[7] += xv * g1.w;
        }
#pragma unroll
        for (int off = 32; off >= 1; off >>= 1) {
#pragma unroll
            for (int e = 0; e < 8; e++) lg[e] += __shfl_xor(lg[e], off, 64);
        }
        float mx = lg[0];
#pragma unroll
        for (int e = 1; e < 8; e++) mx = fmaxf(mx, lg[e]);
        float p[8]; float s = 0.f;
#pragma unroll
        for (int e = 0; e < 8; e++) { p[e] = expf(lg[e] - mx); s += p[e]; }
        float inv = 1.f / s;
#pragma unroll
        for (int e = 0; e < 8; e++) p[e] *= inv;
        float lse = mx + logf(s);
        accZ += lse * lse;
#pragma unroll
        for (int e = 0; e < 8; e++) accP[e] += p[e];
        int e0 = 0; float p0 = p[0]; int e1 = -1; float p1 = -1.f;
#pragma unroll
        for (int e = 1; e < 8; e++) {
            if (p[e] > p0) { e1 = e0; p1 = p0; e0 = e; p0 = p[e]; }
            else if (p[e] > p1) { e1 = e; p1 = p[e]; }
        }
        float sw = p0 + p1;
        float w0 = p0 / sw, w1 = p1 / sw;
        if (lane == 0) {
            *(float4*)&out_logits[n * 8]     = make_float4(lg[0], lg[1], lg[2], lg[3]);
            *(float4*)&out_logits[n * 8 + 4] = make_float4(lg[4], lg[5], lg[6], lg[7]);
            *(float4*)&out_probs[n * 8]      = make_float4(p[0], p[1], p[2], p[3]);
            *(float4*)&out_probs[n * 8 + 4]  = make_float4(p[4], p[5], p[6], p[7]);
            int pos0 = atomicAdd(&counts[e0], 1);
            idx_list[e0 * NTOK + pos0] = n;
            tk_epos[2 * n] = (e0 << 16) | pos0;
            tk_wt[2 * n] = w0;
            int pos1 = atomicAdd(&counts[e1], 1);
            idx_list[e1 * NTOK + pos1] = n;
            tk_epos[2 * n + 1] = (e1 << 16) | pos1;
            tk_wt[2 * n + 1] = w1;
        }
    }
    if (lane == 0) {
#pragma unroll
        for (int e = 0; e < 8; e++) atomicAdd(&psum[e], accP[e]);
        atomicAdd(zsum, accZ);
    }
}

// ---- finalize: prefix offsets + scalar outputs ----
__global__ void k_finalize(const int* __restrict__ counts, const float* __restrict__ psum,
                           const float* __restrict__ zsum, int* __restrict__ offsets,
                           float* __restrict__ out_z, float* __restrict__ out_lbl,
                           float* __restrict__ out_load, float* __restrict__ out_cnt) {
    if (threadIdx.x == 0) {
        int off = 0; float lbl = 0.f;
        for (int e = 0; e < 8; e++) {
            offsets[e] = off; off += counts[e];
            float load = psum[e] * (1.f / NTOK);
            out_load[e] = load;
            out_cnt[e] = (float)counts[e];
            lbl += ((float)counts[e] / (NTOK * 2.f)) * load;
        }
        *out_z = zsum[0] * (1.f / NTOK);
        *out_lbl = 8.f * lbl;
    }
}

// ---- GEMM1: H[slot][F] = gelu(X_gathered @ W1^T' + b1), bf16 out ----
__global__ __launch_bounds__(256) void k_gemm1(const unsigned short* __restrict__ tokb,
                                               const unsigned short* __restrict__ w1t,
                                               const float* __restrict__ b1,
                                               unsigned short* __restrict__ H,
                                               const int* __restrict__ counts,
                                               const int* __restrict__ offsets,
                                               const int* __restrict__ idx_list) {
    int e = blockIdx.z;
    int ne = counts[e];
    int row0 = blockIdx.x * 128;
    if (row0 >= ne) return;
    int col0 = blockIdx.y * 128;
    int offs = offsets[e];

    __shared__ unsigned short As[128 * 64];
    __shared__ unsigned short Bs[128 * 64];

    int tid = threadIdx.x;
    int lane = tid & 63, wv = tid >> 6;
    int wr = wv >> 1, wc = wv & 1;
    int l15 = lane & 15, l4 = lane >> 4;
    int s8 = (tid & 7) * 8;

    const unsigned short* aptr[4];
    const unsigned short* bptr[4];
#pragma unroll
    for (int i = 0; i < 4; i++) {
        int r = i * 32 + (tid >> 3);
        int arow = row0 + r;
        int t = (arow < ne) ? idx_list[e * NTOK + arow] : 0;
        aptr[i] = tokb + (size_t)t * DDIM + s8;
        bptr[i] = w1t + ((size_t)e * FDIM + col0 + r) * DDIM + s8;
    }

    f32x4 acc[4][4];
#pragma unroll
    for (int m = 0; m < 4; m++)
#pragma unroll
        for (int n = 0; n < 4; n++) acc[m][n] = (f32x4)(0.f);

    for (int k0 = 0; k0 < DDIM; k0 += 64) {
        uint4 ar[4], br[4];
#pragma unroll
        for (int i = 0; i < 4; i++) {
            ar[i] = *(const uint4*)(aptr[i] + k0);
            br[i] = *(const uint4*)(bptr[i] + k0);
        }
        __syncthreads();
#pragma unroll
        for (int i = 0; i < 4; i++) {
            *(uint4*)&As[(i * 256 + tid) * 8] = ar[i];
            *(uint4*)&Bs[(i * 256 + tid) * 8] = br[i];
        }
        __syncthreads();
#pragma unroll
        for (int kk = 0; kk < 64; kk += 32) {
            short8 av[4], bv[4];
#pragma unroll
            for (int m = 0; m < 4; m++)
                av[m] = *(const short8*)&As[(wr * 64 + m * 16 + l15) * 64 + kk + l4 * 8];
#pragma unroll
            for (int n = 0; n < 4; n++)
                bv[n] = *(const short8*)&Bs[(wc * 64 + n * 16 + l15) * 64 + kk + l4 * 8];
#pragma unroll
            for (int m = 0; m < 4; m++)
#pragma unroll
                for (int n = 0; n < 4; n++)
                    acc[m][n] = __builtin_amdgcn_mfma_f32_16x16x32_bf16(
                        __builtin_bit_cast(bf16x8, av[m]),
                        __builtin_bit_cast(bf16x8, bv[n]), acc[m][n], 0, 0, 0);
        }
    }
#pragma unroll
    for (int m = 0; m < 4; m++) {
        int rbase = wr * 64 + m * 16 + l4 * 4;
#pragma unroll
        for (int j = 0; j < 4; j++) {
            int r = rbase + j;
            if (row0 + r < ne) {
                size_t hrow = (size_t)(offs + row0 + r) * FDIM;
#pragma unroll
                for (int n = 0; n < 4; n++) {
                    int col = col0 + wc * 64 + n * 16 + l15;
                    float v = acc[m][n][j] + b1[e * FDIM + col];
                    H[hrow + col] = f2bf_bits(gelu_tanh(v));
                }
            }
        }
    }
}

// ---- GEMM2: O[slot][D] = H @ W2 + b2, f32 out ----
__global__ __launch_bounds__(256) void k_gemm2(const unsigned short* __restrict__ H,
                                               const unsigned short* __restrict__ w2t,
                                               const float* __restrict__ b2,
                                               float* __restrict__ O,
                                               const int* __restrict__ counts,
                                               const int* __restrict__ offsets) {
    int e = blockIdx.z;
    int ne = counts[e];
    int row0 = blockIdx.x * 128;
    if (row0 >= ne) return;
    int col0 = blockIdx.y * 128;
    int offs = offsets[e];

    __shared__ unsigned short As[128 * 64];
    __shared__ unsigned short Bs[128 * 64];

    int tid = threadIdx.x;
    int lane = tid & 63, wv = tid >> 6;
    int wr = wv >> 1, wc = wv & 1;
    int l15 = lane & 15, l4 = lane >> 4;
    int s8 = (tid & 7) * 8;

    const unsigned short* aptr[4];
    const unsigned short* bptr[4];
#pragma unroll
    for (int i = 0; i < 4; i++) {
        int r = i * 32 + (tid >> 3);
        int arow = row0 + r;
        int slot = (arow < ne) ? (offs + arow) : 0;
        aptr[i] = H + (size_t)slot * FDIM + s8;
        bptr[i] = w2t + ((size_t)e * DDIM + col0 + r) * FDIM + s8;
    }

    f32x4 acc[4][4];
#pragma unroll
    for (int m = 0; m < 4; m++)
#pragma unroll
        for (int n = 0; n < 4; n++) acc[m][n] = (f32x4)(0.f);

    for (int k0 = 0; k0 < FDIM; k0 += 64) {
        uint4 ar[4], br[4];
#pragma unroll
        for (int i = 0; i < 4; i++) {
            ar[i] = *(const uint4*)(aptr[i] + k0);
            br[i] = *(const uint4*)(bptr[i] + k0);
        }
        __syncthreads();
#pragma unroll
        for (int i = 0; i < 4; i++) {
            *(uint4*)&As[(i * 256 + tid) * 8] = ar[i];
            *(uint4*)&Bs[(i * 256 + tid) * 8] = br[i];
        }
        __syncthreads();
#pragma unroll
        for (int kk = 0; kk < 64; kk += 32) {
            short8 av[4], bv[4];
#pragma unroll
            for (int m = 0; m < 4; m++)
                av[m] = *(const short8*)&As[(wr * 64 + m * 16 + l15) * 64 + kk + l4 * 8];
#pragma unroll
            for (int n = 0; n < 4; n++)
                bv[n] = *(const short8*)&Bs[(wc * 64 + n * 16 + l15) * 64 + kk + l4 * 8];
#pragma unroll
            for (int m = 0; m < 4; m++)
#pragma unroll
                for (int n = 0; n < 4; n++)
                    acc[m][n] = __builtin_amdgcn_mfma_f32_16x16x32_bf16(
                        __builtin_bit_cast(bf16x8, av[m]),
                        __builtin_bit_cast(bf16x8, bv[n]), acc[m][n], 0, 0, 0);
        }
    }
#pragma unroll
    for (int m = 0; m < 4; m++) {
        int rbase = wr * 64 + m * 16 + l4 * 4;
#pragma unroll
        for (int j = 0; j < 4; j++) {
            int r = rbase + j;
            if (row0 + r < ne) {
                size_t orow = (size_t)(offs + row0 + r) * DDIM;
#pragma unroll
                for (int n = 0; n < 4; n++) {
                    int col = col0 + wc * 64 + n * 16 + l15;
                    O[orow + col] = acc[m][n][j] + b2[e * DDIM + col];
                }
            }
        }
    }
}

// ---- combine: out[n] = w0*O[slot0] + w1*O[slot1] ----
__global__ __launch_bounds__(128) void k_combine(const float* __restrict__ O,
                                                 const int* __restrict__ tk_epos,
                                                 const float* __restrict__ tk_wt,
                                                 const int* __restrict__ offsets,
                                                 float* __restrict__ out) {
    int n = blockIdx.x;
    int t = threadIdx.x;  // 128 -> float4 over 512
    int ep0 = tk_epos[2 * n], ep1 = tk_epos[2 * n + 1];
    float w0 = tk_wt[2 * n], w1 = tk_wt[2 * n + 1];
    int s0 = offsets[ep0 >> 16] + (ep0 & 0xFFFF);
    int s1 = offsets[ep1 >> 16] + (ep1 & 0xFFFF);
    const float4* O4 = (const float4*)O;
    float4 a = O4[(size_t)s0 * 128 + t];
    float4 b = O4[(size_t)s1 * 128 + t];
    float4 r;
    r.x = w0 * a.x + w1 * b.x;
    r.y = w0 * a.y + w1 * b.y;
    r.z = w0 * a.z + w1 * b.z;
    r.w = w0 * a.w + w1 * b.w;
    ((float4*)out)[(size_t)n * 128 + t] = r;
}

extern "C" void kernel_launch(void* const* d_in, const int* in_sizes, int n_in,
                              void* d_out, int out_size, void* d_ws, size_t ws_size,
                              hipStream_t stream) {
    const float* h_t    = (const float*)d_in[0];
    const float* gate_w = (const float*)d_in[1];
    const float* w1     = (const float*)d_in[2];
    const float* b1     = (const float*)d_in[3];
    const float* w2     = (const float*)d_in[4];
    const float* b2     = (const float*)d_in[5];
    float* out = (float*)d_out;

    char* ws = (char*)d_ws;
    int*   counts  = (int*)(ws + WS_COUNTS);
    float* psum    = (float*)(ws + WS_PSUM);
    float* zsum    = (float*)(ws + WS_ZSUM);
    int*   offsets = (int*)(ws + WS_OFFSETS);
    int*   tk_epos = (int*)(ws + WS_TKEPOS);
    float* tk_wt   = (float*)(ws + WS_TKWT);
    int*   idx_list= (int*)(ws + WS_IDXLIST);
    unsigned short* tokb = (unsigned short*)(ws + WS_TOKBF);
    unsigned short* w1t  = (unsigned short*)(ws + WS_W1T);
    unsigned short* w2t  = (unsigned short*)(ws + WS_W2T);
    unsigned short* H    = (unsigned short*)(ws + WS_H);
    float* O             = (float*)(ws + WS_O);

    float* out_final  = out;
    float* out_logits = out + 4194304;
    float* out_probs  = out + 4259840;
    float* out_z      = out + 4325376;
    float* out_lbl    = out + 4325377;
    float* out_load   = out + 4325378;
    float* out_cnt    = out + 4325386;

    hipMemsetAsync(d_ws, 0, 256, stream);
    k_convert_tok<<<2048, 256, 0, stream>>>(h_t, tokb);
    k_transpose_bf16<<<dim3(FDIM / 32, DDIM / 32, ENUM), dim3(32, 8), 0, stream>>>(w1, w1t, DDIM, FDIM);
    k_transpose_bf16<<<dim3(DDIM / 32, FDIM / 32, ENUM), dim3(32, 8), 0, stream>>>(w2, w2t, FDIM, DDIM);
    k_gate<<<256, 256, 0, stream>>>(h_t, gate_w, out_logits, out_probs, counts, psum, zsum,
                                    idx_list, tk_epos, tk_wt);
    k_finalize<<<1, 64, 0, stream>>>(counts, psum, zsum, offsets, out_z, out_lbl, out_load, out_cnt);
    k_gemm1<<<dim3(64, 16, ENUM), 256, 0, stream>>>(tokb, w1t, b1, H, counts, offsets, idx_list);
    k_gemm2<<<dim3(64, 4, ENUM), 256, 0, stream>>>(H, w2t, b2, O, counts, offsets);
    k_combine<<<8192, 128, 0, stream>>>(O, tk_epos, tk_wt, offsets, out_final);
}

// Round 2
// 735.484 us; speedup vs baseline: 1.5499x; 1.5499x over previous
//
#include <hip/hip_runtime.h>
#include <hip/hip_bf16.h>

#define NTOK 8192
#define DDIM 512
#define FDIM 2048
#define ENUM 8

typedef __bf16 bf16x8 __attribute__((ext_vector_type(8)));
typedef short short8 __attribute__((ext_vector_type(8)));
typedef unsigned short ushort8 __attribute__((ext_vector_type(8)));
typedef float f32x4 __attribute__((ext_vector_type(4)));

typedef __attribute__((address_space(1))) const unsigned int gu32;
typedef __attribute__((address_space(3))) unsigned int lu32;
#define GLOAD16(g, l) __builtin_amdgcn_global_load_lds((gu32*)(g), (lu32*)(l), 16, 0, 0)

// ---- workspace byte offsets ----
#define WS_COUNTS   0ULL        // int[8]   (zeroed)
#define WS_PSUM     32ULL       // float[8] (zeroed)
#define WS_ZSUM     64ULL       // float    (zeroed)
#define WS_OFFSETS  128ULL      // int[8]
#define WS_TKEPOS   256ULL      // int[2N]
#define WS_TKWT     65792ULL    // float[2N]
#define WS_IDXLIST  131328ULL   // int[E*N]
#define WS_TOKBF    393472ULL   // bf16[N*D]
#define WS_W1T      8782080ULL  // bf16[E*F*D]  (transposed: [e][f][d])
#define WS_W2T      25559296ULL // bf16[E*D*F]  (transposed: [e][d][f])
#define WS_H        42336512ULL // bf16[2N * F]
#define WS_O        109445376ULL// bf16[2N * D]

__device__ __forceinline__ unsigned short f2bf_bits(float f) {
    unsigned int u = __builtin_bit_cast(unsigned int, f);
    unsigned int r = (u + 0x7FFFu + ((u >> 16) & 1u)) >> 16;
    return (unsigned short)r;
}

__device__ __forceinline__ float bf2f(unsigned short s) {
    unsigned int u = ((unsigned int)s) << 16;
    return __builtin_bit_cast(float, u);
}

__device__ __forceinline__ float gelu_tanh(float x) {
    float u = 0.7978845608028654f * (x + 0.044715f * x * x * x);
    return 0.5f * x * (1.0f + tanhf(u));
}

// ---- tokens f32 -> bf16 ----
__global__ __launch_bounds__(256) void k_convert_tok(const float* __restrict__ in,
                                                     unsigned short* __restrict__ out) {
    int i = blockIdx.x * 256 + threadIdx.x;
    const float4* in4 = (const float4*)in;
    float4 a = in4[2 * (size_t)i];
    float4 b = in4[2 * (size_t)i + 1];
    short8 r;
    r[0] = (short)f2bf_bits(a.x); r[1] = (short)f2bf_bits(a.y);
    r[2] = (short)f2bf_bits(a.z); r[3] = (short)f2bf_bits(a.w);
    r[4] = (short)f2bf_bits(b.x); r[5] = (short)f2bf_bits(b.y);
    r[6] = (short)f2bf_bits(b.z); r[7] = (short)f2bf_bits(b.w);
    *(short8*)(out + 8 * (size_t)i) = r;
}

// ---- transpose [E][R][C] f32 -> [E][C][R] bf16 ----
__global__ __launch_bounds__(256) void k_transpose_bf16(const float* __restrict__ in,
                                                        unsigned short* __restrict__ out,
                                                        int R, int C) {
    __shared__ float tile[32][33];
    int e = blockIdx.z;
    int c0 = blockIdx.x << 5, r0 = blockIdx.y << 5;
    const float* ip = in + (size_t)e * R * C;
    unsigned short* op = out + (size_t)e * R * C;
    int tx = threadIdx.x, ty = threadIdx.y;
#pragma unroll
    for (int i = 0; i < 4; i++)
        tile[ty + i * 8][tx] = ip[(size_t)(r0 + ty + i * 8) * C + c0 + tx];
    __syncthreads();
#pragma unroll
    for (int i = 0; i < 4; i++)
        op[(size_t)(c0 + ty + i * 8) * R + r0 + tx] = f2bf_bits(tile[tx][ty + i * 8]);
}

// ---- gating: wave handles 8 tokens ----
__global__ __launch_bounds__(256) void k_gate(const float* __restrict__ tok,
                                              const float* __restrict__ gw,
                                              float* __restrict__ out_logits,
                                              float* __restrict__ out_probs,
                                              int* __restrict__ counts,
                                              float* __restrict__ psum,
                                              float* __restrict__ zsum,
                                              int* __restrict__ idx_list,
                                              int* __restrict__ tk_epos,
                                              float* __restrict__ tk_wt) {
    int lane = threadIdx.x & 63;
    int wid = blockIdx.x * (blockDim.x >> 6) + (threadIdx.x >> 6);
    float accP[8] = {0, 0, 0, 0, 0, 0, 0, 0};
    float accZ = 0.f;
    for (int t = 0; t < 8; ++t) {
        int n = wid * 8 + t;
        const float* tp = tok + (size_t)n * DDIM + lane * 8;
        float4 x0 = *(const float4*)tp;
        float4 x1 = *(const float4*)(tp + 4);
        float lg[8] = {0, 0, 0, 0, 0, 0, 0, 0};
#pragma unroll
        for (int j = 0; j < 8; j++) {
            float xv = (j < 4) ? ((const float*)&x0)[j] : ((const float*)&x1)[j - 4];
            const float4 g0 = *(const float4*)&gw[(lane * 8 + j) * 8];
            const float4 g1 = *(const float4*)&gw[(lane * 8 + j) * 8 + 4];
            lg[0] += xv * g0.x; lg[1] += xv * g0.y; lg[2] += xv * g0.z; lg[3] += xv * g0.w;
            lg[4] += xv * g1.x; lg[5] += xv * g1.y; lg[6] += xv * g1.z; lg[7] += xv * g1.w;
        }
#pragma unroll
        for (int off = 32; off >= 1; off >>= 1) {
#pragma unroll
            for (int e = 0; e < 8; e++) lg[e] += __shfl_xor(lg[e], off, 64);
        }
        float mx = lg[0];
#pragma unroll
        for (int e = 1; e < 8; e++) mx = fmaxf(mx, lg[e]);
        float p[8]; float s = 0.f;
#pragma unroll
        for (int e = 0; e < 8; e++) { p[e] = expf(lg[e] - mx); s += p[e]; }
        float inv = 1.f / s;
#pragma unroll
        for (int e = 0; e < 8; e++) p[e] *= inv;
        float lse = mx + logf(s);
        accZ += lse * lse;
#pragma unroll
        for (int e = 0; e < 8; e++) accP[e] += p[e];
        int e0 = 0; float p0 = p[0]; int e1 = -1; float p1 = -1.f;
#pragma unroll
        for (int e = 1; e < 8; e++) {
            if (p[e] > p0) { e1 = e0; p1 = p0; e0 = e; p0 = p[e]; }
            else if (p[e] > p1) { e1 = e; p1 = p[e]; }
        }
        float sw = p0 + p1;
        float w0 = p0 / sw, w1 = p1 / sw;
        if (lane == 0) {
            *(float4*)&out_logits[n * 8]     = make_float4(lg[0], lg[1], lg[2], lg[3]);
            *(float4*)&out_logits[n * 8 + 4] = make_float4(lg[4], lg[5], lg[6], lg[7]);
            *(float4*)&out_probs[n * 8]      = make_float4(p[0], p[1], p[2], p[3]);
            *(float4*)&out_probs[n * 8 + 4]  = make_float4(p[4], p[5], p[6], p[7]);
            int pos0 = atomicAdd(&counts[e0], 1);
            idx_list[e0 * NTOK + pos0] = n;
            tk_epos[2 * n] = (e0 << 16) | pos0;
            tk_wt[2 * n] = w0;
            int pos1 = atomicAdd(&counts[e1], 1);
            idx_list[e1 * NTOK + pos1] = n;
            tk_epos[2 * n + 1] = (e1 << 16) | pos1;
            tk_wt[2 * n + 1] = w1;
        }
    }
    if (lane == 0) {
#pragma unroll
        for (int e = 0; e < 8; e++) atomicAdd(&psum[e], accP[e]);
        atomicAdd(zsum, accZ);
    }
}

// ---- finalize ----
__global__ void k_finalize(const int* __restrict__ counts, const float* __restrict__ psum,
                           const float* __restrict__ zsum, int* __restrict__ offsets,
                           float* __restrict__ out_z, float* __restrict__ out_lbl,
                           float* __restrict__ out_load, float* __restrict__ out_cnt) {
    if (threadIdx.x == 0) {
        int off = 0; float lbl = 0.f;
        for (int e = 0; e < 8; e++) {
            offsets[e] = off; off += counts[e];
            float load = psum[e] * (1.f / NTOK);
            out_load[e] = load;
            out_cnt[e] = (float)counts[e];
            lbl += ((float)counts[e] / (NTOK * 2.f)) * load;
        }
        *out_z = zsum[0] * (1.f / NTOK);
        *out_lbl = 8.f * lbl;
    }
}

// ---- GEMM1: H = gelu(X_gathered @ W1^T + b1), bf16 out, 2-phase gload_lds ----
__global__ __launch_bounds__(256) void k_gemm1(const unsigned short* __restrict__ tokb,
                                               const unsigned short* __restrict__ w1t,
                                               const float* __restrict__ b1,
                                               unsigned short* __restrict__ H,
                                               const int* __restrict__ counts,
                                               const int* __restrict__ offsets,
                                               const int* __restrict__ idx_list) {
    int e = blockIdx.z;
    int ne = counts[e];
    int row0 = blockIdx.x * 128;
    if (row0 >= ne) return;
    int col0 = blockIdx.y * 128;
    int offs = offsets[e];

    __shared__ unsigned short As[2][8192];
    __shared__ unsigned short Bs[2][8192];

    int tid = threadIdx.x;
    int lane = tid & 63, wv = tid >> 6;
    int wr = wv >> 1, wc = wv & 1;
    int l15 = lane & 15, l4 = lane >> 4;

    const unsigned short* aSrc[4];
    const unsigned short* bSrc[4];
#pragma unroll
    for (int i = 0; i < 4; i++) {
        int r = (wv * 4 + i) * 8 + (lane >> 3);
        int arow = row0 + r;
        int t = (arow < ne) ? idx_list[e * NTOK + arow] : 0;
        aSrc[i] = tokb + (size_t)t * DDIM + (lane & 7) * 8;
        bSrc[i] = w1t + ((size_t)e * FDIM + col0 + r) * DDIM + (lane & 7) * 8;
    }

    float bias[4];
#pragma unroll
    for (int n = 0; n < 4; n++)
        bias[n] = b1[e * FDIM + col0 + wc * 64 + n * 16 + l15];

    f32x4 acc[4][4];
#pragma unroll
    for (int m = 0; m < 4; m++)
#pragma unroll
        for (int n = 0; n < 4; n++) acc[m][n] = (f32x4)(0.f);

    // prologue: stage tile 0
#pragma unroll
    for (int i = 0; i < 4; i++) {
        GLOAD16(aSrc[i], &As[0][(wv * 4 + i) * 512]);
        GLOAD16(bSrc[i], &Bs[0][(wv * 4 + i) * 512]);
    }
    __syncthreads();

    const int NT = DDIM / 64;  // 8
    int cur = 0;
    for (int t = 0; t < NT; ++t) {
        if (t + 1 < NT) {
            int k0 = (t + 1) * 64;
#pragma unroll
            for (int i = 0; i < 4; i++) {
                GLOAD16(aSrc[i] + k0, &As[cur ^ 1][(wv * 4 + i) * 512]);
                GLOAD16(bSrc[i] + k0, &Bs[cur ^ 1][(wv * 4 + i) * 512]);
            }
        }
#pragma unroll
        for (int kk = 0; kk < 64; kk += 32) {
            short8 av[4], bv[4];
#pragma unroll
            for (int m = 0; m < 4; m++)
                av[m] = *(const short8*)&As[cur][(wr * 64 + m * 16 + l15) * 64 + kk + l4 * 8];
#pragma unroll
            for (int n = 0; n < 4; n++)
                bv[n] = *(const short8*)&Bs[cur][(wc * 64 + n * 16 + l15) * 64 + kk + l4 * 8];
#pragma unroll
            for (int m = 0; m < 4; m++)
#pragma unroll
                for (int n = 0; n < 4; n++)
                    acc[m][n] = __builtin_amdgcn_mfma_f32_16x16x32_bf16(
                        __builtin_bit_cast(bf16x8, av[m]),
                        __builtin_bit_cast(bf16x8, bv[n]), acc[m][n], 0, 0, 0);
        }
        __syncthreads();  // drains vmcnt (prefetch) + lgkmcnt
        cur ^= 1;
    }

    // epilogue: gelu+bias -> bf16 -> LDS -> coalesced stores
    unsigned short* Cs = &As[0][0];  // 128x128 bf16 = 32KB
#pragma unroll
    for (int m = 0; m < 4; m++) {
#pragma unroll
        for (int j = 0; j < 4; j++) {
            int r = wr * 64 + m * 16 + l4 * 4 + j;
#pragma unroll
            for (int n = 0; n < 4; n++) {
                int c = wc * 64 + n * 16 + l15;
                float v = acc[m][n][j] + bias[n];
                Cs[r * 128 + c] = f2bf_bits(gelu_tanh(v));
            }
        }
    }
    __syncthreads();
#pragma unroll
    for (int p = 0; p < 8; p++) {
        int r = p * 16 + (tid >> 4);
        int c = (tid & 15) * 8;
        if (row0 + r < ne)
            *(uint4*)&H[(size_t)(offs + row0 + r) * FDIM + col0 + c] =
                *(const uint4*)&Cs[r * 128 + c];
    }
}

// ---- GEMM2: O = H @ W2^T + b2, bf16 out ----
__global__ __launch_bounds__(256) void k_gemm2(const unsigned short* __restrict__ H,
                                               const unsigned short* __restrict__ w2t,
                                               const float* __restrict__ b2,
                                               unsigned short* __restrict__ O,
                                               const int* __restrict__ counts,
                                               const int* __restrict__ offsets) {
    int e = blockIdx.z;
    int ne = counts[e];
    int row0 = blockIdx.x * 128;
    if (row0 >= ne) return;
    int col0 = blockIdx.y * 128;
    int offs = offsets[e];

    __shared__ unsigned short As[2][8192];
    __shared__ unsigned short Bs[2][8192];

    int tid = threadIdx.x;
    int lane = tid & 63, wv = tid >> 6;
    int wr = wv >> 1, wc = wv & 1;
    int l15 = lane & 15, l4 = lane >> 4;

    const unsigned short* aSrc[4];
    const unsigned short* bSrc[4];
#pragma unroll
    for (int i = 0; i < 4; i++) {
        int r = (wv * 4 + i) * 8 + (lane >> 3);
        int arow = row0 + r;
        int slot = (arow < ne) ? (offs + arow) : offs;
        aSrc[i] = H + (size_t)slot * FDIM + (lane & 7) * 8;
        bSrc[i] = w2t + ((size_t)e * DDIM + col0 + r) * FDIM + (lane & 7) * 8;
    }

    float bias[4];
#pragma unroll
    for (int n = 0; n < 4; n++)
        bias[n] = b2[e * DDIM + col0 + wc * 64 + n * 16 + l15];

    f32x4 acc[4][4];
#pragma unroll
    for (int m = 0; m < 4; m++)
#pragma unroll
        for (int n = 0; n < 4; n++) acc[m][n] = (f32x4)(0.f);

#pragma unroll
    for (int i = 0; i < 4; i++) {
        GLOAD16(aSrc[i], &As[0][(wv * 4 + i) * 512]);
        GLOAD16(bSrc[i], &Bs[0][(wv * 4 + i) * 512]);
    }
    __syncthreads();

    const int NT = FDIM / 64;  // 32
    int cur = 0;
    for (int t = 0; t < NT; ++t) {
        if (t + 1 < NT) {
            int k0 = (t + 1) * 64;
#pragma unroll
            for (int i = 0; i < 4; i++) {
                GLOAD16(aSrc[i] + k0, &As[cur ^ 1][(wv * 4 + i) * 512]);
                GLOAD16(bSrc[i] + k0, &Bs[cur ^ 1][(wv * 4 + i) * 512]);
            }
        }
#pragma unroll
        for (int kk = 0; kk < 64; kk += 32) {
            short8 av[4], bv[4];
#pragma unroll
            for (int m = 0; m < 4; m++)
                av[m] = *(const short8*)&As[cur][(wr * 64 + m * 16 + l15) * 64 + kk + l4 * 8];
#pragma unroll
            for (int n = 0; n < 4; n++)
                bv[n] = *(const short8*)&Bs[cur][(wc * 64 + n * 16 + l15) * 64 + kk + l4 * 8];
#pragma unroll
            for (int m = 0; m < 4; m++)
#pragma unroll
                for (int n = 0; n < 4; n++)
                    acc[m][n] = __builtin_amdgcn_mfma_f32_16x16x32_bf16(
                        __builtin_bit_cast(bf16x8, av[m]),
                        __builtin_bit_cast(bf16x8, bv[n]), acc[m][n], 0, 0, 0);
        }
        __syncthreads();
        cur ^= 1;
    }

    unsigned short* Cs = &As[0][0];
#pragma unroll
    for (int m = 0; m < 4; m++) {
#pragma unroll
        for (int j = 0; j < 4; j++) {
            int r = wr * 64 + m * 16 + l4 * 4 + j;
#pragma unroll
            for (int n = 0; n < 4; n++) {
                int c = wc * 64 + n * 16 + l15;
                Cs[r * 128 + c] = f2bf_bits(acc[m][n][j] + bias[n]);
            }
        }
    }
    __syncthreads();
#pragma unroll
    for (int p = 0; p < 8; p++) {
        int r = p * 16 + (tid >> 4);
        int c = (tid & 15) * 8;
        if (row0 + r < ne)
            *(uint4*)&O[(size_t)(offs + row0 + r) * DDIM + col0 + c] =
                *(const uint4*)&Cs[r * 128 + c];
    }
}

// ---- combine: out[n] = w0*O[slot0] + w1*O[slot1] (O is bf16) ----
__global__ __launch_bounds__(256) void k_combine(const unsigned short* __restrict__ O,
                                                 const int* __restrict__ tk_epos,
                                                 const float* __restrict__ tk_wt,
                                                 const int* __restrict__ offsets,
                                                 float* __restrict__ out) {
    int n = blockIdx.x * 4 + (threadIdx.x >> 6);
    int lane = threadIdx.x & 63;
    int ep0 = tk_epos[2 * n], ep1 = tk_epos[2 * n + 1];
    float w0 = tk_wt[2 * n], w1 = tk_wt[2 * n + 1];
    int s0 = offsets[ep0 >> 16] + (ep0 & 0xFFFF);
    int s1 = offsets[ep1 >> 16] + (ep1 & 0xFFFF);
    ushort8 a = *(const ushort8*)&O[(size_t)s0 * DDIM + lane * 8];
    ushort8 b = *(const ushort8*)&O[(size_t)s1 * DDIM + lane * 8];
    float4 r0, r1;
    r0.x = w0 * bf2f(a[0]) + w1 * bf2f(b[0]);
    r0.y = w0 * bf2f(a[1]) + w1 * bf2f(b[1]);
    r0.z = w0 * bf2f(a[2]) + w1 * bf2f(b[2]);
    r0.w = w0 * bf2f(a[3]) + w1 * bf2f(b[3]);
    r1.x = w0 * bf2f(a[4]) + w1 * bf2f(b[4]);
    r1.y = w0 * bf2f(a[5]) + w1 * bf2f(b[5]);
    r1.z = w0 * bf2f(a[6]) + w1 * bf2f(b[6]);
    r1.w = w0 * bf2f(a[7]) + w1 * bf2f(b[7]);
    float* op = out + (size_t)n * DDIM + lane * 8;
    *(float4*)op = r0;
    *(float4*)(op + 4) = r1;
}

extern "C" void kernel_launch(void* const* d_in, const int* in_sizes, int n_in,
                              void* d_out, int out_size, void* d_ws, size_t ws_size,
                              hipStream_t stream) {
    const float* h_t    = (const float*)d_in[0];
    const float* gate_w = (const float*)d_in[1];
    const float* w1     = (const float*)d_in[2];
    const float* b1     = (const float*)d_in[3];
    const float* w2     = (const float*)d_in[4];
    const float* b2     = (const float*)d_in[5];
    float* out = (float*)d_out;

    char* ws = (char*)d_ws;
    int*   counts  = (int*)(ws + WS_COUNTS);
    float* psum    = (float*)(ws + WS_PSUM);
    float* zsum    = (float*)(ws + WS_ZSUM);
    int*   offsets = (int*)(ws + WS_OFFSETS);
    int*   tk_epos = (int*)(ws + WS_TKEPOS);
    float* tk_wt   = (float*)(ws + WS_TKWT);
    int*   idx_list= (int*)(ws + WS_IDXLIST);
    unsigned short* tokb = (unsigned short*)(ws + WS_TOKBF);
    unsigned short* w1t  = (unsigned short*)(ws + WS_W1T);
    unsigned short* w2t  = (unsigned short*)(ws + WS_W2T);
    unsigned short* H    = (unsigned short*)(ws + WS_H);
    unsigned short* O    = (unsigned short*)(ws + WS_O);

    float* out_final  = out;
    float* out_logits = out + 4194304;
    float* out_probs  = out + 4259840;
    float* out_z      = out + 4325376;
    float* out_lbl    = out + 4325377;
    float* out_load   = out + 4325378;
    float* out_cnt    = out + 4325386;

    hipMemsetAsync(d_ws, 0, 256, stream);
    k_convert_tok<<<2048, 256, 0, stream>>>(h_t, tokb);
    k_transpose_bf16<<<dim3(FDIM / 32, DDIM / 32, ENUM), dim3(32, 8), 0, stream>>>(w1, w1t, DDIM, FDIM);
    k_transpose_bf16<<<dim3(DDIM / 32, FDIM / 32, ENUM), dim3(32, 8), 0, stream>>>(w2, w2t, FDIM, DDIM);
    k_gate<<<256, 256, 0, stream>>>(h_t, gate_w, out_logits, out_probs, counts, psum, zsum,
                                    idx_list, tk_epos, tk_wt);
    k_finalize<<<1, 64, 0, stream>>>(counts, psum, zsum, offsets, out_z, out_lbl, out_load, out_cnt);
    k_gemm1<<<dim3(128, 16, ENUM), 256, 0, stream>>>(tokb, w1t, b1, H, counts, offsets, idx_list);
    k_gemm2<<<dim3(128, 4, ENUM), 256, 0, stream>>>(H, w2t, b2, O, counts, offsets);
    k_combine<<<2048, 256, 0, stream>>>(O, tk_epos, tk_wt, offsets, out_final);
}

// Round 5
// 465.133 us; speedup vs baseline: 2.4508x; 1.5812x over previous
//
#include <hip/hip_runtime.h>
#include <hip/hip_bf16.h>

#define NTOK 8192
#define DDIM 512
#define FDIM 2048
#define ENUM 8

typedef __bf16 bf16x8 __attribute__((ext_vector_type(8)));
typedef short short8 __attribute__((ext_vector_type(8)));
typedef unsigned short ushort8 __attribute__((ext_vector_type(8)));
typedef float f32x4 __attribute__((ext_vector_type(4)));

typedef __attribute__((address_space(1))) const unsigned int gu32;
typedef __attribute__((address_space(3))) unsigned int lu32;
#define GLOAD16(g, l) __builtin_amdgcn_global_load_lds((gu32*)(g), (lu32*)(l), 16, 0, 0)

// ---- workspace byte offsets ----
// counts/psum padded: one 128B cacheline per expert to kill atomic serialization.
#define WS_COUNTS   0ULL        // int[8*32]   (zeroed; counts[e*32])
#define WS_PSUM     1024ULL     // float[8*32] (zeroed; psum[e*32])
#define WS_ZSUM     2048ULL     // float       (zeroed)
#define WS_OFFSETS  2176ULL     // int[8]
#define WS_TKEPOS   4096ULL     // int[2N]
#define WS_TKWT     69632ULL    // float[2N]
#define WS_IDXLIST  135168ULL   // int[E*N]
#define WS_TOKBF    397312ULL   // bf16[N*D]
#define WS_W1T      8785920ULL  // bf16[E*F*D]  ([e][f][d])
#define WS_W2T      25563136ULL // bf16[E*D*F]  ([e][d][f])
#define WS_H        42340352ULL // bf16[2N * F]
#define WS_O        109449216ULL// bf16[2N * D]

__device__ __forceinline__ unsigned short f2bf_bits(float f) {
    unsigned int u = __builtin_bit_cast(unsigned int, f);
    unsigned int r = (u + 0x7FFFu + ((u >> 16) & 1u)) >> 16;
    return (unsigned short)r;
}

__device__ __forceinline__ float bf2f(unsigned short s) {
    unsigned int u = ((unsigned int)s) << 16;
    return __builtin_bit_cast(float, u);
}

__device__ __forceinline__ float gelu_tanh(float x) {
    float u = 0.7978845608028654f * (x + 0.044715f * x * x * x);
    return 0.5f * x * (1.0f + tanhf(u));
}

// ---- transpose [E][R][C] f32 -> [E][C][R] bf16 ----
__global__ __launch_bounds__(256) void k_transpose_bf16(const float* __restrict__ in,
                                                        unsigned short* __restrict__ out,
                                                        int R, int C) {
    __shared__ float tile[32][33];
    int e = blockIdx.z;
    int c0 = blockIdx.x << 5, r0 = blockIdx.y << 5;
    const float* ip = in + (size_t)e * R * C;
    unsigned short* op = out + (size_t)e * R * C;
    int tx = threadIdx.x, ty = threadIdx.y;
#pragma unroll
    for (int i = 0; i < 4; i++)
        tile[ty + i * 8][tx] = ip[(size_t)(r0 + ty + i * 8) * C + c0 + tx];
    __syncthreads();
#pragma unroll
    for (int i = 0; i < 4; i++)
        op[(size_t)(c0 + ty + i * 8) * R + r0 + tx] = f2bf_bits(tile[tx][ty + i * 8]);
}

// ---- gating + routing + token bf16 conversion ----
// 128 blocks x 256 threads (4 waves); each wave: 16 tokens; 64 tokens/block.
__global__ __launch_bounds__(256) void k_gate(const float* __restrict__ tok,
                                              const float* __restrict__ gw,
                                              float* __restrict__ out_logits,
                                              float* __restrict__ out_probs,
                                              int* __restrict__ counts,    // padded *32
                                              float* __restrict__ psum,    // padded *32
                                              float* __restrict__ zsum,
                                              int* __restrict__ idx_list,
                                              int* __restrict__ tk_epos,
                                              float* __restrict__ tk_wt,
                                              unsigned short* __restrict__ tokb) {
    __shared__ int lcnt[8];
    __shared__ int gbase[8];
    __shared__ int le[64][2];      // (e<<16)|localpos per token per k
    __shared__ float wred[4][9];   // per-wave psum/z partials

    int tid = threadIdx.x;
    int lane = tid & 63, wv = tid >> 6;
    if (tid < 8) lcnt[tid] = 0;
    __syncthreads();

    float accP[8] = {0, 0, 0, 0, 0, 0, 0, 0};
    float accZ = 0.f;

#pragma unroll 1
    for (int t = 0; t < 16; ++t) {
        int tl = wv * 16 + t;               // token-in-block 0..63
        int n = blockIdx.x * 64 + tl;
        const float* tp = tok + (size_t)n * DDIM + lane * 8;
        float4 x0 = *(const float4*)tp;
        float4 x1 = *(const float4*)(tp + 4);
        // token f32 -> bf16 (fused convert)
        short8 cv;
        cv[0] = (short)f2bf_bits(x0.x); cv[1] = (short)f2bf_bits(x0.y);
        cv[2] = (short)f2bf_bits(x0.z); cv[3] = (short)f2bf_bits(x0.w);
        cv[4] = (short)f2bf_bits(x1.x); cv[5] = (short)f2bf_bits(x1.y);
        cv[6] = (short)f2bf_bits(x1.z); cv[7] = (short)f2bf_bits(x1.w);
        *(short8*)(tokb + (size_t)n * DDIM + lane * 8) = cv;

        float lg[8] = {0, 0, 0, 0, 0, 0, 0, 0};
#pragma unroll
        for (int j = 0; j < 8; j++) {
            float xv = (j < 4) ? ((const float*)&x0)[j] : ((const float*)&x1)[j - 4];
            const float4 g0 = *(const float4*)&gw[(lane * 8 + j) * 8];
            const float4 g1 = *(const float4*)&gw[(lane * 8 + j) * 8 + 4];
            lg[0] += xv * g0.x; lg[1] += xv * g0.y; lg[2] += xv * g0.z; lg[3] += xv * g0.w;
            lg[4] += xv * g1.x; lg[5] += xv * g1.y; lg[6] += xv * g1.z; lg[7] += xv * g1.w;
        }
#pragma unroll
        for (int off = 32; off >= 1; off >>= 1) {
#pragma unroll
            for (int e = 0; e < 8; e++) lg[e] += __shfl_xor(lg[e], off, 64);
        }
        float mx = lg[0];
#pragma unroll
        for (int e = 1; e < 8; e++) mx = fmaxf(mx, lg[e]);
        float p[8]; float s = 0.f;
#pragma unroll
        for (int e = 0; e < 8; e++) { p[e] = expf(lg[e] - mx); s += p[e]; }
        float inv = 1.f / s;
#pragma unroll
        for (int e = 0; e < 8; e++) p[e] *= inv;
        float lse = mx + logf(s);
        accZ += lse * lse;
#pragma unroll
        for (int e = 0; e < 8; e++) accP[e] += p[e];
        int e0 = 0; float p0 = p[0]; int e1 = -1; float p1 = -1.f;
#pragma unroll
        for (int e = 1; e < 8; e++) {
            if (p[e] > p0) { e1 = e0; p1 = p0; e0 = e; p0 = p[e]; }
            else if (p[e] > p1) { e1 = e; p1 = p[e]; }
        }
        float sw = p0 + p1;
        if (lane == 0) {
            *(float4*)&out_logits[n * 8]     = make_float4(lg[0], lg[1], lg[2], lg[3]);
            *(float4*)&out_logits[n * 8 + 4] = make_float4(lg[4], lg[5], lg[6], lg[7]);
            *(float4*)&out_probs[n * 8]      = make_float4(p[0], p[1], p[2], p[3]);
            *(float4*)&out_probs[n * 8 + 4]  = make_float4(p[4], p[5], p[6], p[7]);
            *(float2*)&tk_wt[2 * n] = make_float2(p0 / sw, p1 / sw);
            int pos0 = atomicAdd(&lcnt[e0], 1);
            int pos1 = atomicAdd(&lcnt[e1], 1);
            le[tl][0] = (e0 << 16) | pos0;
            le[tl][1] = (e1 << 16) | pos1;
        }
    }
    if (lane == 0) {
#pragma unroll
        for (int e = 0; e < 8; e++) wred[wv][e] = accP[e];
        wred[wv][8] = accZ;
    }
    __syncthreads();
    if (tid < 8) gbase[tid] = atomicAdd(&counts[tid * 32], lcnt[tid]);
    if (tid < 9) {
        float v = wred[0][tid] + wred[1][tid] + wred[2][tid] + wred[3][tid];
        if (tid < 8) atomicAdd(&psum[tid * 32], v);
        else atomicAdd(zsum, v);
    }
    __syncthreads();
    if (tid < 128) {
        int tl = tid >> 1, k = tid & 1;
        int n = blockIdx.x * 64 + tl;
        int packed = le[tl][k];
        int e = packed >> 16, lpos = packed & 0xFFFF;
        int pos = gbase[e] + lpos;
        idx_list[e * NTOK + pos] = n;
        tk_epos[2 * n + k] = (e << 16) | pos;
    }
}

// ---- finalize ----
__global__ void k_finalize(const int* __restrict__ counts, const float* __restrict__ psum,
                           const float* __restrict__ zsum, int* __restrict__ offsets,
                           float* __restrict__ out_z, float* __restrict__ out_lbl,
                           float* __restrict__ out_load, float* __restrict__ out_cnt) {
    if (threadIdx.x == 0) {
        int off = 0; float lbl = 0.f;
        for (int e = 0; e < 8; e++) {
            int c = counts[e * 32];
            offsets[e] = off; off += c;
            float load = psum[e * 32] * (1.f / NTOK);
            out_load[e] = load;
            out_cnt[e] = (float)c;
            lbl += ((float)c / (NTOK * 2.f)) * load;
        }
        *out_z = zsum[0] * (1.f / NTOK);
        *out_lbl = 8.f * lbl;
    }
}

// ---- GEMM1: H = gelu(X_gathered @ W1^T + b1), bf16 out, 2-phase gload_lds ----
__global__ __launch_bounds__(256) void k_gemm1(const unsigned short* __restrict__ tokb,
                                               const unsigned short* __restrict__ w1t,
                                               const float* __restrict__ b1,
                                               unsigned short* __restrict__ H,
                                               const int* __restrict__ counts,
                                               const int* __restrict__ offsets,
                                               const int* __restrict__ idx_list) {
    int e = blockIdx.z;
    int ne = counts[e * 32];
    int row0 = blockIdx.x * 128;
    if (row0 >= ne) return;
    int col0 = blockIdx.y * 128;
    int offs = offsets[e];

    __shared__ unsigned short As[2][8192];
    __shared__ unsigned short Bs[2][8192];

    int tid = threadIdx.x;
    int lane = tid & 63, wv = tid >> 6;
    int wr = wv >> 1, wc = wv & 1;
    int l15 = lane & 15, l4 = lane >> 4;

    const unsigned short* aSrc[4];
    const unsigned short* bSrc[4];
#pragma unroll
    for (int i = 0; i < 4; i++) {
        int r = (wv * 4 + i) * 8 + (lane >> 3);
        int arow = row0 + r;
        int t = (arow < ne) ? idx_list[e * NTOK + arow] : 0;
        aSrc[i] = tokb + (size_t)t * DDIM + (lane & 7) * 8;
        bSrc[i] = w1t + ((size_t)e * FDIM + col0 + r) * DDIM + (lane & 7) * 8;
    }

    float bias[4];
#pragma unroll
    for (int n = 0; n < 4; n++)
        bias[n] = b1[e * FDIM + col0 + wc * 64 + n * 16 + l15];

    f32x4 acc[4][4];
#pragma unroll
    for (int m = 0; m < 4; m++)
#pragma unroll
        for (int n = 0; n < 4; n++) acc[m][n] = (f32x4)(0.f);

#pragma unroll
    for (int i = 0; i < 4; i++) {
        GLOAD16(aSrc[i], &As[0][(wv * 4 + i) * 512]);
        GLOAD16(bSrc[i], &Bs[0][(wv * 4 + i) * 512]);
    }
    __syncthreads();

    const int NT = DDIM / 64;  // 8
    int cur = 0;
    for (int t = 0; t < NT; ++t) {
        if (t + 1 < NT) {
            int k0 = (t + 1) * 64;
#pragma unroll
            for (int i = 0; i < 4; i++) {
                GLOAD16(aSrc[i] + k0, &As[cur ^ 1][(wv * 4 + i) * 512]);
                GLOAD16(bSrc[i] + k0, &Bs[cur ^ 1][(wv * 4 + i) * 512]);
            }
        }
#pragma unroll
        for (int kk = 0; kk < 64; kk += 32) {
            short8 av[4], bv[4];
#pragma unroll
            for (int m = 0; m < 4; m++)
                av[m] = *(const short8*)&As[cur][(wr * 64 + m * 16 + l15) * 64 + kk + l4 * 8];
#pragma unroll
            for (int n = 0; n < 4; n++)
                bv[n] = *(const short8*)&Bs[cur][(wc * 64 + n * 16 + l15) * 64 + kk + l4 * 8];
#pragma unroll
            for (int m = 0; m < 4; m++)
#pragma unroll
                for (int n = 0; n < 4; n++)
                    acc[m][n] = __builtin_amdgcn_mfma_f32_16x16x32_bf16(
                        __builtin_bit_cast(bf16x8, av[m]),
                        __builtin_bit_cast(bf16x8, bv[n]), acc[m][n], 0, 0, 0);
        }
        __syncthreads();
        cur ^= 1;
    }

    unsigned short* Cs = &As[0][0];
#pragma unroll
    for (int m = 0; m < 4; m++) {
#pragma unroll
        for (int j = 0; j < 4; j++) {
            int r = wr * 64 + m * 16 + l4 * 4 + j;
#pragma unroll
            for (int n = 0; n < 4; n++) {
                int c = wc * 64 + n * 16 + l15;
                float v = acc[m][n][j] + bias[n];
                Cs[r * 128 + c] = f2bf_bits(gelu_tanh(v));
            }
        }
    }
    __syncthreads();
#pragma unroll
    for (int p = 0; p < 8; p++) {
        int r = p * 16 + (tid >> 4);
        int c = (tid & 15) * 8;
        if (row0 + r < ne)
            *(uint4*)&H[(size_t)(offs + row0 + r) * FDIM + col0 + c] =
                *(const uint4*)&Cs[r * 128 + c];
    }
}

// ---- GEMM2: O = H @ W2^T + b2, bf16 out ----
__global__ __launch_bounds__(256) void k_gemm2(const unsigned short* __restrict__ H,
                                               const unsigned short* __restrict__ w2t,
                                               const float* __restrict__ b2,
                                               unsigned short* __restrict__ O,
                                               const int* __restrict__ counts,
                                               const int* __restrict__ offsets) {
    int e = blockIdx.z;
    int ne = counts[e * 32];
    int row0 = blockIdx.x * 128;
    if (row0 >= ne) return;
    int col0 = blockIdx.y * 128;
    int offs = offsets[e];

    __shared__ unsigned short As[2][8192];
    __shared__ unsigned short Bs[2][8192];

    int tid = threadIdx.x;
    int lane = tid & 63, wv = tid >> 6;
    int wr = wv >> 1, wc = wv & 1;
    int l15 = lane & 15, l4 = lane >> 4;

    const unsigned short* aSrc[4];
    const unsigned short* bSrc[4];
#pragma unroll
    for (int i = 0; i < 4; i++) {
        int r = (wv * 4 + i) * 8 + (lane >> 3);
        int arow = row0 + r;
        int slot = (arow < ne) ? (offs + arow) : offs;
        aSrc[i] = H + (size_t)slot * FDIM + (lane & 7) * 8;
        bSrc[i] = w2t + ((size_t)e * DDIM + col0 + r) * FDIM + (lane & 7) * 8;
    }

    float bias[4];
#pragma unroll
    for (int n = 0; n < 4; n++)
        bias[n] = b2[e * DDIM + col0 + wc * 64 + n * 16 + l15];

    f32x4 acc[4][4];
#pragma unroll
    for (int m = 0; m < 4; m++)
#pragma unroll
        for (int n = 0; n < 4; n++) acc[m][n] = (f32x4)(0.f);

#pragma unroll
    for (int i = 0; i < 4; i++) {
        GLOAD16(aSrc[i], &As[0][(wv * 4 + i) * 512]);
        GLOAD16(bSrc[i], &Bs[0][(wv * 4 + i) * 512]);
    }
    __syncthreads();

    const int NT = FDIM / 64;  // 32
    int cur = 0;
    for (int t = 0; t < NT; ++t) {
        if (t + 1 < NT) {
            int k0 = (t + 1) * 64;
#pragma unroll
            for (int i = 0; i < 4; i++) {
                GLOAD16(aSrc[i] + k0, &As[cur ^ 1][(wv * 4 + i) * 512]);
                GLOAD16(bSrc[i] + k0, &Bs[cur ^ 1][(wv * 4 + i) * 512]);
            }
        }
#pragma unroll
        for (int kk = 0; kk < 64; kk += 32) {
            short8 av[4], bv[4];
#pragma unroll
            for (int m = 0; m < 4; m++)
                av[m] = *(const short8*)&As[cur][(wr * 64 + m * 16 + l15) * 64 + kk + l4 * 8];
#pragma unroll
            for (int n = 0; n < 4; n++)
                bv[n] = *(const short8*)&Bs[cur][(wc * 64 + n * 16 + l15) * 64 + kk + l4 * 8];
#pragma unroll
            for (int m = 0; m < 4; m++)
#pragma unroll
                for (int n = 0; n < 4; n++)
                    acc[m][n] = __builtin_amdgcn_mfma_f32_16x16x32_bf16(
                        __builtin_bit_cast(bf16x8, av[m]),
                        __builtin_bit_cast(bf16x8, bv[n]), acc[m][n], 0, 0, 0);
        }
        __syncthreads();
        cur ^= 1;
    }

    unsigned short* Cs = &As[0][0];
#pragma unroll
    for (int m = 0; m < 4; m++) {
#pragma unroll
        for (int j = 0; j < 4; j++) {
            int r = wr * 64 + m * 16 + l4 * 4 + j;
#pragma unroll
            for (int n = 0; n < 4; n++) {
                int c = wc * 64 + n * 16 + l15;
                Cs[r * 128 + c] = f2bf_bits(acc[m][n][j] + bias[n]);
            }
        }
    }
    __syncthreads();
#pragma unroll
    for (int p = 0; p < 8; p++) {
        int r = p * 16 + (tid >> 4);
        int c = (tid & 15) * 8;
        if (row0 + r < ne)
            *(uint4*)&O[(size_t)(offs + row0 + r) * DDIM + col0 + c] =
                *(const uint4*)&Cs[r * 128 + c];
    }
}

// ---- combine: out[n] = w0*O[slot0] + w1*O[slot1] (O is bf16) ----
__global__ __launch_bounds__(256) void k_combine(const unsigned short* __restrict__ O,
                                                 const int* __restrict__ tk_epos,
                                                 const float* __restrict__ tk_wt,
                                                 const int* __restrict__ offsets,
                                                 float* __restrict__ out) {
    int n = blockIdx.x * 4 + (threadIdx.x >> 6);
    int lane = threadIdx.x & 63;
    int ep0 = tk_epos[2 * n], ep1 = tk_epos[2 * n + 1];
    float w0 = tk_wt[2 * n], w1 = tk_wt[2 * n + 1];
    int s0 = offsets[ep0 >> 16] + (ep0 & 0xFFFF);
    int s1 = offsets[ep1 >> 16] + (ep1 & 0xFFFF);
    ushort8 a = *(const ushort8*)&O[(size_t)s0 * DDIM + lane * 8];
    ushort8 b = *(const ushort8*)&O[(size_t)s1 * DDIM + lane * 8];
    float4 r0, r1;
    r0.x = w0 * bf2f(a[0]) + w1 * bf2f(b[0]);
    r0.y = w0 * bf2f(a[1]) + w1 * bf2f(b[1]);
    r0.z = w0 * bf2f(a[2]) + w1 * bf2f(b[2]);
    r0.w = w0 * bf2f(a[3]) + w1 * bf2f(b[3]);
    r1.x = w0 * bf2f(a[4]) + w1 * bf2f(b[4]);
    r1.y = w0 * bf2f(a[5]) + w1 * bf2f(b[5]);
    r1.z = w0 * bf2f(a[6]) + w1 * bf2f(b[6]);
    r1.w = w0 * bf2f(a[7]) + w1 * bf2f(b[7]);
    float* op = out + (size_t)n * DDIM + lane * 8;
    *(float4*)op = r0;
    *(float4*)(op + 4) = r1;
}

extern "C" void kernel_launch(void* const* d_in, const int* in_sizes, int n_in,
                              void* d_out, int out_size, void* d_ws, size_t ws_size,
                              hipStream_t stream) {
    const float* h_t    = (const float*)d_in[0];
    const float* gate_w = (const float*)d_in[1];
    const float* w1     = (const float*)d_in[2];
    const float* b1     = (const float*)d_in[3];
    const float* w2     = (const float*)d_in[4];
    const float* b2     = (const float*)d_in[5];
    float* out = (float*)d_out;

    char* ws = (char*)d_ws;
    int*   counts  = (int*)(ws + WS_COUNTS);
    float* psum    = (float*)(ws + WS_PSUM);
    float* zsum    = (float*)(ws + WS_ZSUM);
    int*   offsets = (int*)(ws + WS_OFFSETS);
    int*   tk_epos = (int*)(ws + WS_TKEPOS);
    float* tk_wt   = (float*)(ws + WS_TKWT);
    int*   idx_list= (int*)(ws + WS_IDXLIST);
    unsigned short* tokb = (unsigned short*)(ws + WS_TOKBF);
    unsigned short* w1t  = (unsigned short*)(ws + WS_W1T);
    unsigned short* w2t  = (unsigned short*)(ws + WS_W2T);
    unsigned short* H    = (unsigned short*)(ws + WS_H);
    unsigned short* O    = (unsigned short*)(ws + WS_O);

    float* out_final  = out;
    float* out_logits = out + 4194304;
    float* out_probs  = out + 4259840;
    float* out_z      = out + 4325376;
    float* out_lbl    = out + 4325377;
    float* out_load   = out + 4325378;
    float* out_cnt    = out + 4325386;

    hipMemsetAsync(d_ws, 0, 4096, stream);
    k_gate<<<128, 256, 0, stream>>>(h_t, gate_w, out_logits, out_probs, counts, psum, zsum,
                                    idx_list, tk_epos, tk_wt, tokb);
    k_transpose_bf16<<<dim3(FDIM / 32, DDIM / 32, ENUM), dim3(32, 8), 0, stream>>>(w1, w1t, DDIM, FDIM);
    k_transpose_bf16<<<dim3(DDIM / 32, FDIM / 32, ENUM), dim3(32, 8), 0, stream>>>(w2, w2t, FDIM, DDIM);
    k_finalize<<<1, 64, 0, stream>>>(counts, psum, zsum, offsets, out_z, out_lbl, out_load, out_cnt);
    k_gemm1<<<dim3(128, 16, ENUM), 256, 0, stream>>>(tokb, w1t, b1, H, counts, offsets, idx_list);
    k_gemm2<<<dim3(128, 4, ENUM), 256, 0, stream>>>(H, w2t, b2, O, counts, offsets);
    k_combine<<<2048, 256, 0, stream>>>(O, tk_epos, tk_wt, offsets, out_final);
}

// Round 6
// 455.673 us; speedup vs baseline: 2.5017x; 1.0208x over previous
//
#include <hip/hip_runtime.h>
#include <hip/hip_bf16.h>

#define NTOK 8192
#define DDIM 512
#define FDIM 2048
#define ENUM 8

typedef __bf16 bf16x8 __attribute__((ext_vector_type(8)));
typedef short short8 __attribute__((ext_vector_type(8)));
typedef unsigned short ushort8 __attribute__((ext_vector_type(8)));
typedef float f32x4 __attribute__((ext_vector_type(4)));

typedef __attribute__((address_space(1))) const unsigned int gu32;
typedef __attribute__((address_space(3))) unsigned int lu32;
#define GLOAD16(g, l) __builtin_amdgcn_global_load_lds((gu32*)(g), (lu32*)(l), 16, 0, 0)

#define MFMA16(a, b, c) __builtin_amdgcn_mfma_f32_16x16x32_bf16( \
    __builtin_bit_cast(bf16x8, a), __builtin_bit_cast(bf16x8, b), c, 0, 0, 0)

// ---- workspace byte offsets ----
#define WS_COUNTS   0ULL        // int[8*32]   (zeroed; counts[e*32])
#define WS_PSUM     1024ULL     // float[8*32] (zeroed; psum[e*32])
#define WS_ZSUM     2048ULL     // float       (zeroed)
#define WS_OFFSETS  2176ULL     // int[8]
#define WS_TKEPOS   4096ULL     // int[2N]
#define WS_TKWT     69632ULL    // float[2N]
#define WS_IDXLIST  135168ULL   // int[E*N]
#define WS_TOKBF    397312ULL   // bf16[N*D]
#define WS_W1T      8785920ULL  // bf16[E*F*D]  ([e][f][d])
#define WS_W2T      25563136ULL // bf16[E*D*F]  ([e][d][f])
#define WS_H        42340352ULL // bf16[2N * F]
#define WS_O        109449216ULL// bf16[2N * D]

__device__ __forceinline__ unsigned short f2bf_bits(float f) {
    unsigned int u = __builtin_bit_cast(unsigned int, f);
    unsigned int r = (u + 0x7FFFu + ((u >> 16) & 1u)) >> 16;
    return (unsigned short)r;
}

__device__ __forceinline__ float bf2f(unsigned short s) {
    unsigned int u = ((unsigned int)s) << 16;
    return __builtin_bit_cast(float, u);
}

// gelu(x)=0.5x(1+tanh(u)) == x*sigmoid(2u), u=0.79788456*(x+0.044715x^3)
__device__ __forceinline__ float gelu_fast(float x) {
    float t = 1.5957691216057308f * x * (1.0f + 0.044715f * x * x);
    return x * __builtin_amdgcn_rcpf(1.0f + __expf(-t));
}

// ---- transpose [E][R][C] f32 -> [E][C][R] bf16 ----
__global__ __launch_bounds__(256) void k_transpose_bf16(const float* __restrict__ in,
                                                        unsigned short* __restrict__ out,
                                                        int R, int C) {
    __shared__ float tile[32][33];
    int e = blockIdx.z;
    int c0 = blockIdx.x << 5, r0 = blockIdx.y << 5;
    const float* ip = in + (size_t)e * R * C;
    unsigned short* op = out + (size_t)e * R * C;
    int tx = threadIdx.x, ty = threadIdx.y;
#pragma unroll
    for (int i = 0; i < 4; i++)
        tile[ty + i * 8][tx] = ip[(size_t)(r0 + ty + i * 8) * C + c0 + tx];
    __syncthreads();
#pragma unroll
    for (int i = 0; i < 4; i++)
        op[(size_t)(c0 + ty + i * 8) * R + r0 + tx] = f2bf_bits(tile[tx][ty + i * 8]);
}

// ---- gating + routing + token bf16 conversion ----
__global__ __launch_bounds__(256) void k_gate(const float* __restrict__ tok,
                                              const float* __restrict__ gw,
                                              float* __restrict__ out_logits,
                                              float* __restrict__ out_probs,
                                              int* __restrict__ counts,    // padded *32
                                              float* __restrict__ psum,    // padded *32
                                              float* __restrict__ zsum,
                                              int* __restrict__ idx_list,
                                              int* __restrict__ tk_epos,
                                              float* __restrict__ tk_wt,
                                              unsigned short* __restrict__ tokb) {
    __shared__ int lcnt[8];
    __shared__ int gbase[8];
    __shared__ int le[64][2];
    __shared__ float wred[4][9];

    int tid = threadIdx.x;
    int lane = tid & 63, wv = tid >> 6;
    if (tid < 8) lcnt[tid] = 0;
    __syncthreads();

    float accP[8] = {0, 0, 0, 0, 0, 0, 0, 0};
    float accZ = 0.f;

#pragma unroll 1
    for (int t = 0; t < 16; ++t) {
        int tl = wv * 16 + t;
        int n = blockIdx.x * 64 + tl;
        const float* tp = tok + (size_t)n * DDIM + lane * 8;
        float4 x0 = *(const float4*)tp;
        float4 x1 = *(const float4*)(tp + 4);
        short8 cv;
        cv[0] = (short)f2bf_bits(x0.x); cv[1] = (short)f2bf_bits(x0.y);
        cv[2] = (short)f2bf_bits(x0.z); cv[3] = (short)f2bf_bits(x0.w);
        cv[4] = (short)f2bf_bits(x1.x); cv[5] = (short)f2bf_bits(x1.y);
        cv[6] = (short)f2bf_bits(x1.z); cv[7] = (short)f2bf_bits(x1.w);
        *(short8*)(tokb + (size_t)n * DDIM + lane * 8) = cv;

        float lg[8] = {0, 0, 0, 0, 0, 0, 0, 0};
#pragma unroll
        for (int j = 0; j < 8; j++) {
            float xv = (j < 4) ? ((const float*)&x0)[j] : ((const float*)&x1)[j - 4];
            const float4 g0 = *(const float4*)&gw[(lane * 8 + j) * 8];
            const float4 g1 = *(const float4*)&gw[(lane * 8 + j) * 8 + 4];
            lg[0] += xv * g0.x; lg[1] += xv * g0.y; lg[2] += xv * g0.z; lg[3] += xv * g0.w;
            lg[4] += xv * g1.x; lg[5] += xv * g1.y; lg[6] += xv * g1.z; lg[7] += xv * g1.w;
        }
#pragma unroll
        for (int off = 32; off >= 1; off >>= 1) {
#pragma unroll
            for (int e = 0; e < 8; e++) lg[e] += __shfl_xor(lg[e], off, 64);
        }
        float mx = lg[0];
#pragma unroll
        for (int e = 1; e < 8; e++) mx = fmaxf(mx, lg[e]);
        float p[8]; float s = 0.f;
#pragma unroll
        for (int e = 0; e < 8; e++) { p[e] = expf(lg[e] - mx); s += p[e]; }
        float inv = 1.f / s;
#pragma unroll
        for (int e = 0; e < 8; e++) p[e] *= inv;
        float lse = mx + logf(s);
        accZ += lse * lse;
#pragma unroll
        for (int e = 0; e < 8; e++) accP[e] += p[e];
        int e0 = 0; float p0 = p[0]; int e1 = -1; float p1 = -1.f;
#pragma unroll
        for (int e = 1; e < 8; e++) {
            if (p[e] > p0) { e1 = e0; p1 = p0; e0 = e; p0 = p[e]; }
            else if (p[e] > p1) { e1 = e; p1 = p[e]; }
        }
        float sw = p0 + p1;
        if (lane == 0) {
            *(float4*)&out_logits[n * 8]     = make_float4(lg[0], lg[1], lg[2], lg[3]);
            *(float4*)&out_logits[n * 8 + 4] = make_float4(lg[4], lg[5], lg[6], lg[7]);
            *(float4*)&out_probs[n * 8]      = make_float4(p[0], p[1], p[2], p[3]);
            *(float4*)&out_probs[n * 8 + 4]  = make_float4(p[4], p[5], p[6], p[7]);
            *(float2*)&tk_wt[2 * n] = make_float2(p0 / sw, p1 / sw);
            int pos0 = atomicAdd(&lcnt[e0], 1);
            int pos1 = atomicAdd(&lcnt[e1], 1);
            le[tl][0] = (e0 << 16) | pos0;
            le[tl][1] = (e1 << 16) | pos1;
        }
    }
    if (lane == 0) {
#pragma unroll
        for (int e = 0; e < 8; e++) wred[wv][e] = accP[e];
        wred[wv][8] = accZ;
    }
    __syncthreads();
    if (tid < 8) gbase[tid] = atomicAdd(&counts[tid * 32], lcnt[tid]);
    if (tid < 9) {
        float v = wred[0][tid] + wred[1][tid] + wred[2][tid] + wred[3][tid];
        if (tid < 8) atomicAdd(&psum[tid * 32], v);
        else atomicAdd(zsum, v);
    }
    __syncthreads();
    if (tid < 128) {
        int tl = tid >> 1, k = tid & 1;
        int n = blockIdx.x * 64 + tl;
        int packed = le[tl][k];
        int e = packed >> 16, lpos = packed & 0xFFFF;
        int pos = gbase[e] + lpos;
        idx_list[e * NTOK + pos] = n;
        tk_epos[2 * n + k] = (e << 16) | pos;
    }
}

// ---- finalize ----
__global__ void k_finalize(const int* __restrict__ counts, const float* __restrict__ psum,
                           const float* __restrict__ zsum, int* __restrict__ offsets,
                           float* __restrict__ out_z, float* __restrict__ out_lbl,
                           float* __restrict__ out_load, float* __restrict__ out_cnt) {
    if (threadIdx.x == 0) {
        int off = 0; float lbl = 0.f;
        for (int e = 0; e < 8; e++) {
            int c = counts[e * 32];
            offsets[e] = off; off += c;
            float load = psum[e * 32] * (1.f / NTOK);
            out_load[e] = load;
            out_cnt[e] = (float)c;
            lbl += ((float)c / (NTOK * 2.f)) * load;
        }
        *out_z = zsum[0] * (1.f / NTOK);
        *out_lbl = 8.f * lbl;
    }
}

// ---- GEMM1: 256x256 tile, 8 waves, 2-phase gload_lds, swizzled LDS ----
// H = gelu(X_gathered @ W1T^T + b1), bf16 out.
__global__ __launch_bounds__(512, 2) void k_gemm1(const unsigned short* __restrict__ tokb,
                                                  const unsigned short* __restrict__ w1t,
                                                  const float* __restrict__ b1,
                                                  unsigned short* __restrict__ H,
                                                  const int* __restrict__ counts,
                                                  const int* __restrict__ offsets,
                                                  const int* __restrict__ idx_list) {
    int e = blockIdx.z;
    int ne = counts[e * 32];
    int row0 = blockIdx.x * 256;
    if (row0 >= ne) return;
    int col0 = blockIdx.y * 256;
    int offs = offsets[e];

    // 128KB: As[0]|As[1] = SH+0, SH+16384 ; Bs[0]|Bs[1] = SH+32768, SH+49152 (u16 idx)
    __shared__ __align__(16) unsigned short SH[65536];

    int tid = threadIdx.x;
    int lane = tid & 63, wv = tid >> 6;
    int wr = wv >> 2, wc = wv & 3;          // 2 x 4 wave grid; wave tile 128x64
    int l15 = lane & 15, l4 = lane >> 4;
    int lr3 = lane >> 3, lch = lane & 7;
    int sch = lch ^ lr3;                    // pre-swizzled global source chunk

    const unsigned short* aS[4];
    const unsigned short* bS[4];
#pragma unroll
    for (int p = 0; p < 4; p++) {
        int r = p * 64 + wv * 8 + lr3;      // tile row this lane stages
        int ar = row0 + r;
        int tkn = (ar < ne) ? idx_list[e * NTOK + ar] : 0;
        aS[p] = tokb + (size_t)tkn * DDIM + sch * 8;
        bS[p] = w1t + ((size_t)e * FDIM + col0 + r) * DDIM + sch * 8;
    }

    float bias[4];
#pragma unroll
    for (int n = 0; n < 4; n++)
        bias[n] = b1[e * FDIM + col0 + wc * 64 + n * 16 + l15];

    f32x4 acc[8][4];
#pragma unroll
    for (int m = 0; m < 8; m++)
#pragma unroll
        for (int n = 0; n < 4; n++) acc[m][n] = (f32x4)(0.f);

#pragma unroll
    for (int p = 0; p < 4; p++) {
        GLOAD16(aS[p], SH + p * 4096 + wv * 512);
        GLOAD16(bS[p], SH + 32768 + p * 4096 + wv * 512);
    }
    __syncthreads();

    int sw = (l15 & 7) << 3;
    int cur = 0;
#pragma unroll 1
    for (int t = 0; t < 8; ++t) {
        if (t < 7) {
            int k0 = (t + 1) * 64;
            int nb = cur ^ 1;
#pragma unroll
            for (int p = 0; p < 4; p++) {
                GLOAD16(aS[p] + k0, SH + nb * 16384 + p * 4096 + wv * 512);
                GLOAD16(bS[p] + k0, SH + 32768 + nb * 16384 + p * 4096 + wv * 512);
            }
        }
        const unsigned short* Ac = SH + cur * 16384;
        const unsigned short* Bc = SH + 32768 + cur * 16384;
#pragma unroll
        for (int kk = 0; kk < 2; kk++) {
            int cofs = (kk * 32 + l4 * 8) ^ sw;   // swizzled read offset
            short8 av[8], bv[4];
#pragma unroll
            for (int m = 0; m < 8; m++)
                av[m] = *(const short8*)&Ac[(wr * 128 + m * 16 + l15) * 64 + cofs];
#pragma unroll
            for (int n = 0; n < 4; n++)
                bv[n] = *(const short8*)&Bc[(wc * 64 + n * 16 + l15) * 64 + cofs];
#pragma unroll
            for (int m = 0; m < 8; m++)
#pragma unroll
                for (int n = 0; n < 4; n++)
                    acc[m][n] = MFMA16(av[m], bv[n], acc[m][n]);
        }
        __syncthreads();
        cur ^= 1;
    }

    // epilogue: per-wave private 16KB LDS slice, no extra barrier
    unsigned short* Cw = SH + wv * 8192;    // [128][64] bf16
#pragma unroll
    for (int m = 0; m < 8; m++)
#pragma unroll
        for (int n = 0; n < 4; n++)
#pragma unroll
            for (int j = 0; j < 4; j++) {
                int lr2 = m * 16 + l4 * 4 + j;
                float v = acc[m][n][j] + bias[n];
                Cw[lr2 * 64 + n * 16 + l15] = f2bf_bits(gelu_fast(v));
            }
#pragma unroll
    for (int p2 = 0; p2 < 16; p2++) {
        int lr = p2 * 8 + lr3;
        int gr = row0 + wr * 128 + lr;
        if (gr < ne)
            *(uint4*)&H[(size_t)(offs + gr) * FDIM + col0 + wc * 64 + lch * 8] =
                *(const uint4*)&Cw[lr * 64 + lch * 8];
    }
}

// ---- GEMM2: 256x128 tile, 8 waves, 2-phase gload_lds, swizzled LDS ----
// O = H @ W2T^T + b2, bf16 out.
__global__ __launch_bounds__(512, 2) void k_gemm2(const unsigned short* __restrict__ H,
                                                  const unsigned short* __restrict__ w2t,
                                                  const float* __restrict__ b2,
                                                  unsigned short* __restrict__ O,
                                                  const int* __restrict__ counts,
                                                  const int* __restrict__ offsets) {
    int e = blockIdx.z;
    int ne = counts[e * 32];
    int row0 = blockIdx.x * 256;
    if (row0 >= ne) return;
    int col0 = blockIdx.y * 128;
    int offs = offsets[e];

    // 96KB: As[0]=0, As[1]=16384 ; Bs[0]=32768, Bs[1]=40960 (u16 idx)
    __shared__ __align__(16) unsigned short SH[49152];

    int tid = threadIdx.x;
    int lane = tid & 63, wv = tid >> 6;
    int wr = wv >> 1, wc = wv & 1;          // 4 x 2 wave grid; wave tile 64x64
    int l15 = lane & 15, l4 = lane >> 4;
    int lr3 = lane >> 3, lch = lane & 7;
    int sch = lch ^ lr3;

    const unsigned short* aS[4];
    const unsigned short* bS[2];
#pragma unroll
    for (int p = 0; p < 4; p++) {
        int r = p * 64 + wv * 8 + lr3;
        int ar = row0 + r;
        int slot = (ar < ne) ? (offs + ar) : 0;
        aS[p] = H + (size_t)slot * FDIM + sch * 8;
    }
#pragma unroll
    for (int p = 0; p < 2; p++) {
        int r = p * 64 + wv * 8 + lr3;      // 0..127
        bS[p] = w2t + ((size_t)e * DDIM + col0 + r) * FDIM + sch * 8;
    }

    float bias[4];
#pragma unroll
    for (int n = 0; n < 4; n++)
        bias[n] = b2[e * DDIM + col0 + wc * 64 + n * 16 + l15];

    f32x4 acc[4][4];
#pragma unroll
    for (int m = 0; m < 4; m++)
#pragma unroll
        for (int n = 0; n < 4; n++) acc[m][n] = (f32x4)(0.f);

#pragma unroll
    for (int p = 0; p < 4; p++) GLOAD16(aS[p], SH + p * 4096 + wv * 512);
#pragma unroll
    for (int p = 0; p < 2; p++) GLOAD16(bS[p], SH + 32768 + p * 4096 + wv * 512);
    __syncthreads();

    int sw = (l15 & 7) << 3;
    int cur = 0;
#pragma unroll 1
    for (int t = 0; t < 32; ++t) {
        if (t < 31) {
            int k0 = (t + 1) * 64;
            int nb = cur ^ 1;
#pragma unroll
            for (int p = 0; p < 4; p++)
                GLOAD16(aS[p] + k0, SH + nb * 16384 + p * 4096 + wv * 512);
#pragma unroll
            for (int p = 0; p < 2; p++)
                GLOAD16(bS[p] + k0, SH + 32768 + nb * 8192 + p * 4096 + wv * 512);
        }
        const unsigned short* Ac = SH + cur * 16384;
        const unsigned short* Bc = SH + 32768 + cur * 8192;
#pragma unroll
        for (int kk = 0; kk < 2; kk++) {
            int cofs = (kk * 32 + l4 * 8) ^ sw;
            short8 av[4], bv[4];
#pragma unroll
            for (int m = 0; m < 4; m++)
                av[m] = *(const short8*)&Ac[(wr * 64 + m * 16 + l15) * 64 + cofs];
#pragma unroll
            for (int n = 0; n < 4; n++)
                bv[n] = *(const short8*)&Bc[(wc * 64 + n * 16 + l15) * 64 + cofs];
#pragma unroll
            for (int m = 0; m < 4; m++)
#pragma unroll
                for (int n = 0; n < 4; n++)
                    acc[m][n] = MFMA16(av[m], bv[n], acc[m][n]);
        }
        __syncthreads();
        cur ^= 1;
    }

    // epilogue: per-wave private 8KB slice
    unsigned short* Cw = SH + wv * 4096;    // [64][64] bf16
#pragma unroll
    for (int m = 0; m < 4; m++)
#pragma unroll
        for (int n = 0; n < 4; n++)
#pragma unroll
            for (int j = 0; j < 4; j++) {
                int lr2 = m * 16 + l4 * 4 + j;
                Cw[lr2 * 64 + n * 16 + l15] = f2bf_bits(acc[m][n][j] + bias[n]);
            }
#pragma unroll
    for (int p2 = 0; p2 < 8; p2++) {
        int lr = p2 * 8 + lr3;
        int gr = row0 + wr * 64 + lr;
        if (gr < ne)
            *(uint4*)&O[(size_t)(offs + gr) * DDIM + col0 + wc * 64 + lch * 8] =
                *(const uint4*)&Cw[lr * 64 + lch * 8];
    }
}

// ---- combine: out[n] = w0*O[slot0] + w1*O[slot1] (O is bf16) ----
__global__ __launch_bounds__(256) void k_combine(const unsigned short* __restrict__ O,
                                                 const int* __restrict__ tk_epos,
                                                 const float* __restrict__ tk_wt,
                                                 const int* __restrict__ offsets,
                                                 float* __restrict__ out) {
    int n = blockIdx.x * 4 + (threadIdx.x >> 6);
    int lane = threadIdx.x & 63;
    int ep0 = tk_epos[2 * n], ep1 = tk_epos[2 * n + 1];
    float w0 = tk_wt[2 * n], w1 = tk_wt[2 * n + 1];
    int s0 = offsets[ep0 >> 16] + (ep0 & 0xFFFF);
    int s1 = offsets[ep1 >> 16] + (ep1 & 0xFFFF);
    ushort8 a = *(const ushort8*)&O[(size_t)s0 * DDIM + lane * 8];
    ushort8 b = *(const ushort8*)&O[(size_t)s1 * DDIM + lane * 8];
    float4 r0, r1;
    r0.x = w0 * bf2f(a[0]) + w1 * bf2f(b[0]);
    r0.y = w0 * bf2f(a[1]) + w1 * bf2f(b[1]);
    r0.z = w0 * bf2f(a[2]) + w1 * bf2f(b[2]);
    r0.w = w0 * bf2f(a[3]) + w1 * bf2f(b[3]);
    r1.x = w0 * bf2f(a[4]) + w1 * bf2f(b[4]);
    r1.y = w0 * bf2f(a[5]) + w1 * bf2f(b[5]);
    r1.z = w0 * bf2f(a[6]) + w1 * bf2f(b[6]);
    r1.w = w0 * bf2f(a[7]) + w1 * bf2f(b[7]);
    float* op = out + (size_t)n * DDIM + lane * 8;
    *(float4*)op = r0;
    *(float4*)(op + 4) = r1;
}

extern "C" void kernel_launch(void* const* d_in, const int* in_sizes, int n_in,
                              void* d_out, int out_size, void* d_ws, size_t ws_size,
                              hipStream_t stream) {
    const float* h_t    = (const float*)d_in[0];
    const float* gate_w = (const float*)d_in[1];
    const float* w1     = (const float*)d_in[2];
    const float* b1     = (const float*)d_in[3];
    const float* w2     = (const float*)d_in[4];
    const float* b2     = (const float*)d_in[5];
    float* out = (float*)d_out;

    char* ws = (char*)d_ws;
    int*   counts  = (int*)(ws + WS_COUNTS);
    float* psum    = (float*)(ws + WS_PSUM);
    float* zsum    = (float*)(ws + WS_ZSUM);
    int*   offsets = (int*)(ws + WS_OFFSETS);
    int*   tk_epos = (int*)(ws + WS_TKEPOS);
    float* tk_wt   = (float*)(ws + WS_TKWT);
    int*   idx_list= (int*)(ws + WS_IDXLIST);
    unsigned short* tokb = (unsigned short*)(ws + WS_TOKBF);
    unsigned short* w1t  = (unsigned short*)(ws + WS_W1T);
    unsigned short* w2t  = (unsigned short*)(ws + WS_W2T);
    unsigned short* H    = (unsigned short*)(ws + WS_H);
    unsigned short* O    = (unsigned short*)(ws + WS_O);

    float* out_final  = out;
    float* out_logits = out + 4194304;
    float* out_probs  = out + 4259840;
    float* out_z      = out + 4325376;
    float* out_lbl    = out + 4325377;
    float* out_load   = out + 4325378;
    float* out_cnt    = out + 4325386;

    hipMemsetAsync(d_ws, 0, 4096, stream);
    k_gate<<<128, 256, 0, stream>>>(h_t, gate_w, out_logits, out_probs, counts, psum, zsum,
                                    idx_list, tk_epos, tk_wt, tokb);
    k_transpose_bf16<<<dim3(FDIM / 32, DDIM / 32, ENUM), dim3(32, 8), 0, stream>>>(w1, w1t, DDIM, FDIM);
    k_transpose_bf16<<<dim3(DDIM / 32, FDIM / 32, ENUM), dim3(32, 8), 0, stream>>>(w2, w2t, FDIM, DDIM);
    k_finalize<<<1, 64, 0, stream>>>(counts, psum, zsum, offsets, out_z, out_lbl, out_load, out_cnt);
    k_gemm1<<<dim3(64, 8, ENUM), 512, 0, stream>>>(tokb, w1t, b1, H, counts, offsets, idx_list);
    k_gemm2<<<dim3(64, 4, ENUM), 512, 0, stream>>>(H, w2t, b2, O, counts, offsets);
    k_combine<<<2048, 256, 0, stream>>>(O, tk_epos, tk_wt, offsets, out_final);
}

// Round 7
// 306.859 us; speedup vs baseline: 3.7149x; 1.4850x over previous
//
#include <hip/hip_runtime.h>
#include <hip/hip_bf16.h>

#define NTOK 8192
#define DDIM 512
#define FDIM 2048
#define ENUM 8
#define MAXT 72   // max row-tiles of 256 across experts: sum ceil(ne/256) <= 64+7

typedef __bf16 bf16x8 __attribute__((ext_vector_type(8)));
typedef short short8 __attribute__((ext_vector_type(8)));
typedef unsigned short ushort8 __attribute__((ext_vector_type(8)));
typedef float f32x4 __attribute__((ext_vector_type(4)));

typedef __attribute__((address_space(1))) const unsigned int gu32;
typedef __attribute__((address_space(3))) unsigned int lu32;
#define GLOAD16(g, l) __builtin_amdgcn_global_load_lds((gu32*)(g), (lu32*)(l), 16, 0, 0)

#define MFMA16(a, b, c) __builtin_amdgcn_mfma_f32_16x16x32_bf16( \
    __builtin_bit_cast(bf16x8, a), __builtin_bit_cast(bf16x8, b), c, 0, 0, 0)

// ---- workspace byte offsets ----
#define WS_COUNTS   0ULL        // int[8*32]   (zeroed; counts[e*32])
#define WS_PSUM     1024ULL     // float[8*32] (zeroed; psum[e*32])
#define WS_ZSUM     2048ULL     // float       (zeroed)
#define WS_OFFSETS  2176ULL     // int[8]
#define WS_TILEMAP  2304ULL     // int[MAXT]
#define WS_TKEPOS   4096ULL     // int[2N]
#define WS_TKWT     69632ULL    // float[2N]
#define WS_IDXLIST  135168ULL   // int[E*N]
#define WS_TOKBF    397312ULL   // bf16[N*D]
#define WS_W1T      8785920ULL  // bf16[E*F*D]  ([e][f][d])
#define WS_W2T      25563136ULL // bf16[E*D*F]  ([e][d][f])
#define WS_H        42340352ULL // bf16[2N * F]
#define WS_O        109449216ULL// bf16[2N * D]

__device__ __forceinline__ unsigned short f2bf_bits(float f) {
    unsigned int u = __builtin_bit_cast(unsigned int, f);
    unsigned int r = (u + 0x7FFFu + ((u >> 16) & 1u)) >> 16;
    return (unsigned short)r;
}

__device__ __forceinline__ float bf2f(unsigned short s) {
    unsigned int u = ((unsigned int)s) << 16;
    return __builtin_bit_cast(float, u);
}

// gelu(x)=0.5x(1+tanh(u)) == x*sigmoid(2u), u=0.79788456*(x+0.044715x^3)
__device__ __forceinline__ float gelu_fast(float x) {
    float t = 1.5957691216057308f * x * (1.0f + 0.044715f * x * x);
    return x * __builtin_amdgcn_rcpf(1.0f + __expf(-t));
}

// ---- transpose [E][R][C] f32 -> [E][C][R] bf16 ----
__global__ __launch_bounds__(256) void k_transpose_bf16(const float* __restrict__ in,
                                                        unsigned short* __restrict__ out,
                                                        int R, int C) {
    __shared__ float tile[32][33];
    int e = blockIdx.z;
    int c0 = blockIdx.x << 5, r0 = blockIdx.y << 5;
    const float* ip = in + (size_t)e * R * C;
    unsigned short* op = out + (size_t)e * R * C;
    int tx = threadIdx.x, ty = threadIdx.y;
#pragma unroll
    for (int i = 0; i < 4; i++)
        tile[ty + i * 8][tx] = ip[(size_t)(r0 + ty + i * 8) * C + c0 + tx];
    __syncthreads();
#pragma unroll
    for (int i = 0; i < 4; i++)
        op[(size_t)(c0 + ty + i * 8) * R + r0 + tx] = f2bf_bits(tile[tx][ty + i * 8]);
}

// ---- gating + routing + token bf16 conversion ----
__global__ __launch_bounds__(256) void k_gate(const float* __restrict__ tok,
                                              const float* __restrict__ gw,
                                              float* __restrict__ out_logits,
                                              float* __restrict__ out_probs,
                                              int* __restrict__ counts,    // padded *32
                                              float* __restrict__ psum,    // padded *32
                                              float* __restrict__ zsum,
                                              int* __restrict__ idx_list,
                                              int* __restrict__ tk_epos,
                                              float* __restrict__ tk_wt,
                                              unsigned short* __restrict__ tokb) {
    __shared__ int lcnt[8];
    __shared__ int gbase[8];
    __shared__ int le[64][2];
    __shared__ float wred[4][9];

    int tid = threadIdx.x;
    int lane = tid & 63, wv = tid >> 6;
    if (tid < 8) lcnt[tid] = 0;
    __syncthreads();

    float accP[8] = {0, 0, 0, 0, 0, 0, 0, 0};
    float accZ = 0.f;

#pragma unroll 1
    for (int t = 0; t < 16; ++t) {
        int tl = wv * 16 + t;
        int n = blockIdx.x * 64 + tl;
        const float* tp = tok + (size_t)n * DDIM + lane * 8;
        float4 x0 = *(const float4*)tp;
        float4 x1 = *(const float4*)(tp + 4);
        short8 cv;
        cv[0] = (short)f2bf_bits(x0.x); cv[1] = (short)f2bf_bits(x0.y);
        cv[2] = (short)f2bf_bits(x0.z); cv[3] = (short)f2bf_bits(x0.w);
        cv[4] = (short)f2bf_bits(x1.x); cv[5] = (short)f2bf_bits(x1.y);
        cv[6] = (short)f2bf_bits(x1.z); cv[7] = (short)f2bf_bits(x1.w);
        *(short8*)(tokb + (size_t)n * DDIM + lane * 8) = cv;

        float lg[8] = {0, 0, 0, 0, 0, 0, 0, 0};
#pragma unroll
        for (int j = 0; j < 8; j++) {
            float xv = (j < 4) ? ((const float*)&x0)[j] : ((const float*)&x1)[j - 4];
            const float4 g0 = *(const float4*)&gw[(lane * 8 + j) * 8];
            const float4 g1 = *(const float4*)&gw[(lane * 8 + j) * 8 + 4];
            lg[0] += xv * g0.x; lg[1] += xv * g0.y; lg[2] += xv * g0.z; lg[3] += xv * g0.w;
            lg[4] += xv * g1.x; lg[5] += xv * g1.y; lg[6] += xv * g1.z; lg[7] += xv * g1.w;
        }
#pragma unroll
        for (int off = 32; off >= 1; off >>= 1) {
#pragma unroll
            for (int e = 0; e < 8; e++) lg[e] += __shfl_xor(lg[e], off, 64);
        }
        float mx = lg[0];
#pragma unroll
        for (int e = 1; e < 8; e++) mx = fmaxf(mx, lg[e]);
        float p[8]; float s = 0.f;
#pragma unroll
        for (int e = 0; e < 8; e++) { p[e] = expf(lg[e] - mx); s += p[e]; }
        float inv = 1.f / s;
#pragma unroll
        for (int e = 0; e < 8; e++) p[e] *= inv;
        float lse = mx + logf(s);
        accZ += lse * lse;
#pragma unroll
        for (int e = 0; e < 8; e++) accP[e] += p[e];
        int e0 = 0; float p0 = p[0]; int e1 = -1; float p1 = -1.f;
#pragma unroll
        for (int e = 1; e < 8; e++) {
            if (p[e] > p0) { e1 = e0; p1 = p0; e0 = e; p0 = p[e]; }
            else if (p[e] > p1) { e1 = e; p1 = p[e]; }
        }
        float sw = p0 + p1;
        if (lane == 0) {
            *(float4*)&out_logits[n * 8]     = make_float4(lg[0], lg[1], lg[2], lg[3]);
            *(float4*)&out_logits[n * 8 + 4] = make_float4(lg[4], lg[5], lg[6], lg[7]);
            *(float4*)&out_probs[n * 8]      = make_float4(p[0], p[1], p[2], p[3]);
            *(float4*)&out_probs[n * 8 + 4]  = make_float4(p[4], p[5], p[6], p[7]);
            *(float2*)&tk_wt[2 * n] = make_float2(p0 / sw, p1 / sw);
            int pos0 = atomicAdd(&lcnt[e0], 1);
            int pos1 = atomicAdd(&lcnt[e1], 1);
            le[tl][0] = (e0 << 16) | pos0;
            le[tl][1] = (e1 << 16) | pos1;
        }
    }
    if (lane == 0) {
#pragma unroll
        for (int e = 0; e < 8; e++) wred[wv][e] = accP[e];
        wred[wv][8] = accZ;
    }
    __syncthreads();
    if (tid < 8) gbase[tid] = atomicAdd(&counts[tid * 32], lcnt[tid]);
    if (tid < 9) {
        float v = wred[0][tid] + wred[1][tid] + wred[2][tid] + wred[3][tid];
        if (tid < 8) atomicAdd(&psum[tid * 32], v);
        else atomicAdd(zsum, v);
    }
    __syncthreads();
    if (tid < 128) {
        int tl = tid >> 1, k = tid & 1;
        int n = blockIdx.x * 64 + tl;
        int packed = le[tl][k];
        int e = packed >> 16, lpos = packed & 0xFFFF;
        int pos = gbase[e] + lpos;
        idx_list[e * NTOK + pos] = n;
        tk_epos[2 * n + k] = (e << 16) | pos;
    }
}

// ---- finalize: offsets, scalar outputs, and the balanced tile map ----
__global__ void k_finalize(const int* __restrict__ counts, const float* __restrict__ psum,
                           const float* __restrict__ zsum, int* __restrict__ offsets,
                           int* __restrict__ tilemap,
                           float* __restrict__ out_z, float* __restrict__ out_lbl,
                           float* __restrict__ out_load, float* __restrict__ out_cnt) {
    if (threadIdx.x == 0) {
        int off = 0; float lbl = 0.f; int nt = 0;
        for (int e = 0; e < 8; e++) {
            int c = counts[e * 32];
            offsets[e] = off; off += c;
            float load = psum[e * 32] * (1.f / NTOK);
            out_load[e] = load;
            out_cnt[e] = (float)c;
            lbl += ((float)c / (NTOK * 2.f)) * load;
            int t = (c + 255) >> 8;
            for (int i = 0; i < t; i++) tilemap[nt++] = (e << 16) | i;
        }
        for (; nt < MAXT; nt++) tilemap[nt] = -1;
        *out_z = zsum[0] * (1.f / NTOK);
        *out_lbl = 8.f * lbl;
    }
}

// ---- GEMM1: 256x256 tile, 8 waves, 2-phase gload_lds, swizzled LDS, tile-map dispatch ----
__global__ __launch_bounds__(512, 2) void k_gemm1(const unsigned short* __restrict__ tokb,
                                                  const unsigned short* __restrict__ w1t,
                                                  const float* __restrict__ b1,
                                                  unsigned short* __restrict__ H,
                                                  const int* __restrict__ counts,
                                                  const int* __restrict__ offsets,
                                                  const int* __restrict__ tilemap,
                                                  const int* __restrict__ idx_list) {
    int tm = tilemap[blockIdx.x];
    if (tm < 0) return;
    int e = tm >> 16;
    int ne = counts[e * 32];
    int row0 = (tm & 0xFFFF) * 256;
    int col0 = blockIdx.y * 256;
    int offs = offsets[e];

    __shared__ __align__(16) unsigned short SH[65536];

    int tid = threadIdx.x;
    int lane = tid & 63, wv = tid >> 6;
    int wr = wv >> 2, wc = wv & 3;          // 2 x 4 wave grid; wave tile 128x64
    int l15 = lane & 15, l4 = lane >> 4;
    int lr3 = lane >> 3, lch = lane & 7;
    int sch = lch ^ lr3;                    // pre-swizzled global source chunk

    const unsigned short* aS[4];
    const unsigned short* bS[4];
#pragma unroll
    for (int p = 0; p < 4; p++) {
        int r = p * 64 + wv * 8 + lr3;
        int ar = row0 + r;
        int tkn = (ar < ne) ? idx_list[e * NTOK + ar] : 0;
        aS[p] = tokb + (size_t)tkn * DDIM + sch * 8;
        bS[p] = w1t + ((size_t)e * FDIM + col0 + r) * DDIM + sch * 8;
    }

    float bias[4];
#pragma unroll
    for (int n = 0; n < 4; n++)
        bias[n] = b1[e * FDIM + col0 + wc * 64 + n * 16 + l15];

    f32x4 acc[8][4];
#pragma unroll
    for (int m = 0; m < 8; m++)
#pragma unroll
        for (int n = 0; n < 4; n++) acc[m][n] = (f32x4)(0.f);

#pragma unroll
    for (int p = 0; p < 4; p++) {
        GLOAD16(aS[p], SH + p * 4096 + wv * 512);
        GLOAD16(bS[p], SH + 32768 + p * 4096 + wv * 512);
    }
    __syncthreads();

    int sw = (l15 & 7) << 3;
    int cur = 0;
#pragma unroll 1
    for (int t = 0; t < 8; ++t) {
        if (t < 7) {
            int k0 = (t + 1) * 64;
            int nb = cur ^ 1;
#pragma unroll
            for (int p = 0; p < 4; p++) {
                GLOAD16(aS[p] + k0, SH + nb * 16384 + p * 4096 + wv * 512);
                GLOAD16(bS[p] + k0, SH + 32768 + nb * 16384 + p * 4096 + wv * 512);
            }
        }
        const unsigned short* Ac = SH + cur * 16384;
        const unsigned short* Bc = SH + 32768 + cur * 16384;
#pragma unroll
        for (int kk = 0; kk < 2; kk++) {
            int cofs = (kk * 32 + l4 * 8) ^ sw;
            short8 av[8], bv[4];
#pragma unroll
            for (int m = 0; m < 8; m++)
                av[m] = *(const short8*)&Ac[(wr * 128 + m * 16 + l15) * 64 + cofs];
#pragma unroll
            for (int n = 0; n < 4; n++)
                bv[n] = *(const short8*)&Bc[(wc * 64 + n * 16 + l15) * 64 + cofs];
#pragma unroll
            for (int m = 0; m < 8; m++)
#pragma unroll
                for (int n = 0; n < 4; n++)
                    acc[m][n] = MFMA16(av[m], bv[n], acc[m][n]);
        }
        __syncthreads();
        cur ^= 1;
    }

    unsigned short* Cw = SH + wv * 8192;    // [128][64] bf16 per-wave slice
#pragma unroll
    for (int m = 0; m < 8; m++)
#pragma unroll
        for (int n = 0; n < 4; n++)
#pragma unroll
            for (int j = 0; j < 4; j++) {
                int lr2 = m * 16 + l4 * 4 + j;
                float v = acc[m][n][j] + bias[n];
                Cw[lr2 * 64 + n * 16 + l15] = f2bf_bits(gelu_fast(v));
            }
#pragma unroll
    for (int p2 = 0; p2 < 16; p2++) {
        int lr = p2 * 8 + lr3;
        int gr = row0 + wr * 128 + lr;
        if (gr < ne)
            *(uint4*)&H[(size_t)(offs + gr) * FDIM + col0 + wc * 64 + lch * 8] =
                *(const uint4*)&Cw[lr * 64 + lch * 8];
    }
}

// ---- GEMM2: 256x128 tile, 8 waves, 2-phase gload_lds, swizzled LDS, tile-map dispatch ----
__global__ __launch_bounds__(512, 2) void k_gemm2(const unsigned short* __restrict__ H,
                                                  const unsigned short* __restrict__ w2t,
                                                  const float* __restrict__ b2,
                                                  unsigned short* __restrict__ O,
                                                  const int* __restrict__ counts,
                                                  const int* __restrict__ offsets,
                                                  const int* __restrict__ tilemap) {
    int tm = tilemap[blockIdx.x];
    if (tm < 0) return;
    int e = tm >> 16;
    int ne = counts[e * 32];
    int row0 = (tm & 0xFFFF) * 256;
    int col0 = blockIdx.y * 128;
    int offs = offsets[e];

    __shared__ __align__(16) unsigned short SH[49152];

    int tid = threadIdx.x;
    int lane = tid & 63, wv = tid >> 6;
    int wr = wv >> 1, wc = wv & 1;          // 4 x 2 wave grid; wave tile 64x64
    int l15 = lane & 15, l4 = lane >> 4;
    int lr3 = lane >> 3, lch = lane & 7;
    int sch = lch ^ lr3;

    const unsigned short* aS[4];
    const unsigned short* bS[2];
#pragma unroll
    for (int p = 0; p < 4; p++) {
        int r = p * 64 + wv * 8 + lr3;
        int ar = row0 + r;
        int slot = (ar < ne) ? (offs + ar) : 0;
        aS[p] = H + (size_t)slot * FDIM + sch * 8;
    }
#pragma unroll
    for (int p = 0; p < 2; p++) {
        int r = p * 64 + wv * 8 + lr3;      // 0..127
        bS[p] = w2t + ((size_t)e * DDIM + col0 + r) * FDIM + sch * 8;
    }

    float bias[4];
#pragma unroll
    for (int n = 0; n < 4; n++)
        bias[n] = b2[e * DDIM + col0 + wc * 64 + n * 16 + l15];

    f32x4 acc[4][4];
#pragma unroll
    for (int m = 0; m < 4; m++)
#pragma unroll
        for (int n = 0; n < 4; n++) acc[m][n] = (f32x4)(0.f);

#pragma unroll
    for (int p = 0; p < 4; p++) GLOAD16(aS[p], SH + p * 4096 + wv * 512);
#pragma unroll
    for (int p = 0; p < 2; p++) GLOAD16(bS[p], SH + 32768 + p * 4096 + wv * 512);
    __syncthreads();

    int sw = (l15 & 7) << 3;
    int cur = 0;
#pragma unroll 1
    for (int t = 0; t < 32; ++t) {
        if (t < 31) {
            int k0 = (t + 1) * 64;
            int nb = cur ^ 1;
#pragma unroll
            for (int p = 0; p < 4; p++)
                GLOAD16(aS[p] + k0, SH + nb * 16384 + p * 4096 + wv * 512);
#pragma unroll
            for (int p = 0; p < 2; p++)
                GLOAD16(bS[p] + k0, SH + 32768 + nb * 8192 + p * 4096 + wv * 512);
        }
        const unsigned short* Ac = SH + cur * 16384;
        const unsigned short* Bc = SH + 32768 + cur * 8192;
#pragma unroll
        for (int kk = 0; kk < 2; kk++) {
            int cofs = (kk * 32 + l4 * 8) ^ sw;
            short8 av[4], bv[4];
#pragma unroll
            for (int m = 0; m < 4; m++)
                av[m] = *(const short8*)&Ac[(wr * 64 + m * 16 + l15) * 64 + cofs];
#pragma unroll
            for (int n = 0; n < 4; n++)
                bv[n] = *(const short8*)&Bc[(wc * 64 + n * 16 + l15) * 64 + cofs];
#pragma unroll
            for (int m = 0; m < 4; m++)
#pragma unroll
                for (int n = 0; n < 4; n++)
                    acc[m][n] = MFMA16(av[m], bv[n], acc[m][n]);
        }
        __syncthreads();
        cur ^= 1;
    }

    unsigned short* Cw = SH + wv * 4096;    // [64][64] bf16 per-wave slice
#pragma unroll
    for (int m = 0; m < 4; m++)
#pragma unroll
        for (int n = 0; n < 4; n++)
#pragma unroll
            for (int j = 0; j < 4; j++) {
                int lr2 = m * 16 + l4 * 4 + j;
                Cw[lr2 * 64 + n * 16 + l15] = f2bf_bits(acc[m][n][j] + bias[n]);
            }
#pragma unroll
    for (int p2 = 0; p2 < 8; p2++) {
        int lr = p2 * 8 + lr3;
        int gr = row0 + wr * 64 + lr;
        if (gr < ne)
            *(uint4*)&O[(size_t)(offs + gr) * DDIM + col0 + wc * 64 + lch * 8] =
                *(const uint4*)&Cw[lr * 64 + lch * 8];
    }
}

// ---- combine: out[n] = w0*O[slot0] + w1*O[slot1] (O is bf16) ----
__global__ __launch_bounds__(256) void k_combine(const unsigned short* __restrict__ O,
                                                 const int* __restrict__ tk_epos,
                                                 const float* __restrict__ tk_wt,
                                                 const int* __restrict__ offsets,
                                                 float* __restrict__ out) {
    int n = blockIdx.x * 4 + (threadIdx.x >> 6);
    int lane = threadIdx.x & 63;
    int ep0 = tk_epos[2 * n], ep1 = tk_epos[2 * n + 1];
    float w0 = tk_wt[2 * n], w1 = tk_wt[2 * n + 1];
    int s0 = offsets[ep0 >> 16] + (ep0 & 0xFFFF);
    int s1 = offsets[ep1 >> 16] + (ep1 & 0xFFFF);
    ushort8 a = *(const ushort8*)&O[(size_t)s0 * DDIM + lane * 8];
    ushort8 b = *(const ushort8*)&O[(size_t)s1 * DDIM + lane * 8];
    float4 r0, r1;
    r0.x = w0 * bf2f(a[0]) + w1 * bf2f(b[0]);
    r0.y = w0 * bf2f(a[1]) + w1 * bf2f(b[1]);
    r0.z = w0 * bf2f(a[2]) + w1 * bf2f(b[2]);
    r0.w = w0 * bf2f(a[3]) + w1 * bf2f(b[3]);
    r1.x = w0 * bf2f(a[4]) + w1 * bf2f(b[4]);
    r1.y = w0 * bf2f(a[5]) + w1 * bf2f(b[5]);
    r1.z = w0 * bf2f(a[6]) + w1 * bf2f(b[6]);
    r1.w = w0 * bf2f(a[7]) + w1 * bf2f(b[7]);
    float* op = out + (size_t)n * DDIM + lane * 8;
    *(float4*)op = r0;
    *(float4*)(op + 4) = r1;
}

extern "C" void kernel_launch(void* const* d_in, const int* in_sizes, int n_in,
                              void* d_out, int out_size, void* d_ws, size_t ws_size,
                              hipStream_t stream) {
    const float* h_t    = (const float*)d_in[0];
    const float* gate_w = (const float*)d_in[1];
    const float* w1     = (const float*)d_in[2];
    const float* b1     = (const float*)d_in[3];
    const float* w2     = (const float*)d_in[4];
    const float* b2     = (const float*)d_in[5];
    float* out = (float*)d_out;

    char* ws = (char*)d_ws;
    int*   counts  = (int*)(ws + WS_COUNTS);
    float* psum    = (float*)(ws + WS_PSUM);
    float* zsum    = (float*)(ws + WS_ZSUM);
    int*   offsets = (int*)(ws + WS_OFFSETS);
    int*   tilemap = (int*)(ws + WS_TILEMAP);
    int*   tk_epos = (int*)(ws + WS_TKEPOS);
    float* tk_wt   = (float*)(ws + WS_TKWT);
    int*   idx_list= (int*)(ws + WS_IDXLIST);
    unsigned short* tokb = (unsigned short*)(ws + WS_TOKBF);
    unsigned short* w1t  = (unsigned short*)(ws + WS_W1T);
    unsigned short* w2t  = (unsigned short*)(ws + WS_W2T);
    unsigned short* H    = (unsigned short*)(ws + WS_H);
    unsigned short* O    = (unsigned short*)(ws + WS_O);

    float* out_final  = out;
    float* out_logits = out + 4194304;
    float* out_probs  = out + 4259840;
    float* out_z      = out + 4325376;
    float* out_lbl    = out + 4325377;
    float* out_load   = out + 4325378;
    float* out_cnt    = out + 4325386;

    hipMemsetAsync(d_ws, 0, 4096, stream);
    k_gate<<<128, 256, 0, stream>>>(h_t, gate_w, out_logits, out_probs, counts, psum, zsum,
                                    idx_list, tk_epos, tk_wt, tokb);
    k_transpose_bf16<<<dim3(FDIM / 32, DDIM / 32, ENUM), dim3(32, 8), 0, stream>>>(w1, w1t, DDIM, FDIM);
    k_transpose_bf16<<<dim3(DDIM / 32, FDIM / 32, ENUM), dim3(32, 8), 0, stream>>>(w2, w2t, FDIM, DDIM);
    k_finalize<<<1, 64, 0, stream>>>(counts, psum, zsum, offsets, tilemap,
                                     out_z, out_lbl, out_load, out_cnt);
    k_gemm1<<<dim3(MAXT, 8), 512, 0, stream>>>(tokb, w1t, b1, H, counts, offsets, tilemap, idx_list);
    k_gemm2<<<dim3(MAXT, 4), 512, 0, stream>>>(H, w2t, b2, O, counts, offsets, tilemap);
    k_combine<<<2048, 256, 0, stream>>>(O, tk_epos, tk_wt, offsets, out_final);
}